// Round 18
// baseline (7005.466 us; speedup 1.0000x reference)
//
#include <hip/hip_runtime.h>
#include <cstdint>
#include <cstddef>

// ---------- types ----------
typedef float     f32x4 __attribute__((ext_vector_type(4)));
typedef _Float16  f16x8 __attribute__((ext_vector_type(8)));
typedef _Float16  f16x4 __attribute__((ext_vector_type(4)));
typedef _Float16  f16x2 __attribute__((ext_vector_type(2)));

#define GLD16(g, l)                                                            \
  __builtin_amdgcn_global_load_lds(                                           \
      (const __attribute__((address_space(1))) void*)(g),                     \
      (__attribute__((address_space(3))) void*)(l), 16, 0, 0)

// ---------- constants ----------
#define BQ    4
#define SEQ   1024
#define DMOD  768
#define NH    12
#define DKH   64
#define DVH   128
#define DVAL  1536
#define DFFN  3072
#define BS    4096   /* BQ*SEQ */

// =====================================================================
// theta-shift trig table: ct/st[s][jp], jp=0..31
// =====================================================================
__global__ void trig_kernel(float* __restrict__ ct, float* __restrict__ st)
{
  int s = blockIdx.x, jp = threadIdx.x;   // 1024 x 32
  float ang = exp2f(-(float)jp * (13.287712379549449f / 31.f));
  float a = (float)s * ang;
  ct[s * 32 + jp] = cosf(a);
  st[s * 32 + jp] = sinf(a);
}

// =====================================================================
// weight transpose + f32->f16 hi/lo split into fused layout.
// mode 0: orow = row_off + n  (linear)
// mode 1: fc1 interleave : orow = (n>>6)*128 + ((n>>5)&1)*64 + (n&31)
// mode 2: gate interleave: orow = (n>>6)*128 + ((n>>5)&1)*64 + 32 + (n&31)
// =====================================================================
__global__ void wcvt_kernel(const float* __restrict__ win, _Float16* __restrict__ whi,
                            _Float16* __restrict__ wlo, int K, int N,
                            long in_ls, long out_ls, int row_off, int mode)
{
  __shared__ float tle[32][33];
  size_t ib = (size_t)blockIdx.z * in_ls;
  size_t ob = (size_t)blockIdx.z * out_ls;
  int k0 = blockIdx.y * 32, n0 = blockIdx.x * 32;
  int tx = threadIdx.x, ty = threadIdx.y;
#pragma unroll
  for (int i = 0; i < 4; ++i)
    tle[ty + 8*i][tx] = win[ib + (size_t)(k0 + ty + 8*i) * N + n0 + tx];
  __syncthreads();
#pragma unroll
  for (int i = 0; i < 4; ++i) {
    float v = tle[tx][ty + 8*i];
    _Float16 h = (_Float16)v;
    int n = n0 + ty + 8*i;
    int orow;
    if (mode == 0)      orow = row_off + n;
    else if (mode == 1) orow = (n >> 6) * 128 + ((n >> 5) & 1) * 64 + (n & 31);
    else                orow = (n >> 6) * 128 + ((n >> 5) & 1) * 64 + 32 + (n & 31);
    size_t idx = ob + (size_t)orow * K + k0 + tx;
    whi[idx] = h;
    wlo[idx] = (_Float16)((v - (float)h) * 1024.0f);
  }
}

// =====================================================================
// embedding gather
// =====================================================================
__global__ void embed_kernel(const int* __restrict__ ids, const float* __restrict__ emb,
                             float* __restrict__ x)
{
  int tok = blockIdx.x;
  int id  = ids[tok];
  const float4* s = (const float4*)(emb + (size_t)id * DMOD);
  float4*       d = (float4*)(x + (size_t)tok * DMOD);
  d[threadIdx.x] = s[threadIdx.x];   // block = 192 threads
}

// =====================================================================
// layernorm over 768 -> f32 out (final LN)
// =====================================================================
__global__ __launch_bounds__(256) void ln_kernel(const float* __restrict__ x,
                                                 const float* __restrict__ g,
                                                 const float* __restrict__ bta,
                                                 float* __restrict__ out)
{
  int row = blockIdx.x;
  const float* xr = x + (size_t)row * DMOD;
  int t = threadIdx.x;
  float v0 = xr[t], v1 = xr[t + 256], v2 = xr[t + 512];
  float s  = v0 + v1 + v2;
  float sq = v0*v0 + v1*v1 + v2*v2;
#pragma unroll
  for (int m = 1; m < 64; m <<= 1) { s += __shfl_xor(s, m); sq += __shfl_xor(sq, m); }
  __shared__ float red[8];
  int wv = t >> 6, ln_ = t & 63;
  if (ln_ == 0) { red[wv] = s; red[wv + 4] = sq; }
  __syncthreads();
  s  = red[0] + red[1] + red[2] + red[3];
  sq = red[4] + red[5] + red[6] + red[7];
  float mu = s * (1.f / DMOD);
  float rs = rsqrtf(sq * (1.f / DMOD) - mu * mu + 1e-5f);
  out[(size_t)row * DMOD + t      ] = (v0 - mu) * rs * g[t      ] + bta[t      ];
  out[(size_t)row * DMOD + t + 256] = (v1 - mu) * rs * g[t + 256] + bta[t + 256];
  out[(size_t)row * DMOD + t + 512] = (v2 - mu) * rs * g[t + 512] + bta[t + 512];
}

// =====================================================================
// layernorm over 768 -> f16 (GEMM A-operand)
// =====================================================================
__global__ __launch_bounds__(256) void ln_h_kernel(const float* __restrict__ x,
                                                   const float* __restrict__ g,
                                                   const float* __restrict__ bta,
                                                   _Float16* __restrict__ oh)
{
  int row = blockIdx.x;
  const float* xr = x + (size_t)row * DMOD;
  int t = threadIdx.x;
  float v0 = xr[t], v1 = xr[t + 256], v2 = xr[t + 512];
  float s  = v0 + v1 + v2;
  float sq = v0*v0 + v1*v1 + v2*v2;
#pragma unroll
  for (int m = 1; m < 64; m <<= 1) { s += __shfl_xor(s, m); sq += __shfl_xor(sq, m); }
  __shared__ float red[8];
  int wv = t >> 6, ln_ = t & 63;
  if (ln_ == 0) { red[wv] = s; red[wv + 4] = sq; }
  __syncthreads();
  s  = red[0] + red[1] + red[2] + red[3];
  sq = red[4] + red[5] + red[6] + red[7];
  float mu = s * (1.f / DMOD);
  float rs = rsqrtf(sq * (1.f / DMOD) - mu * mu + 1e-5f);
#pragma unroll
  for (int q = 0; q < 3; ++q) {
    int c = t + q * 256;
    float y = (xr[c] - mu) * rs * g[c] + bta[c];
    oh[(size_t)row * DMOD + c] = (_Float16)y;
  }
}

// =====================================================================
// GEMM: A[M][K](f16) @ (Bh + Bl/1024)[NTOT][K](f16)^T, 2-term split.
// BM x 128 tile, BK=32, TPB/64 waves, global_load_lds, XCD swizzle,
// N-fastest traversal, 2-buffer pipeline, conflict-free LDS swizzle.
// MODE 0: C f32 (opt += R).  MODE 1: silu-gate f16.  MODE 2: split-K
// atomic.  MODE 3: fused qkvg epilogue.
// =====================================================================
template<int BM, int MODE, int TPB>
__global__ __launch_bounds__(TPB) void gemm_bt(const _Float16* __restrict__ Ah,
                                               const _Float16* __restrict__ Bh,
                                               const _Float16* __restrict__ Bl,
                                               float* __restrict__ C,
                                               const float* __restrict__ R,
                                               _Float16* __restrict__ OH,
                                               _Float16* __restrict__ qH,
                                               _Float16* __restrict__ qL,
                                               _Float16* __restrict__ kH,
                                               _Float16* __restrict__ kL,
                                               _Float16* __restrict__ vtb,
                                               _Float16* __restrict__ gb,
                                               const float* __restrict__ ct,
                                               const float* __restrict__ st,
                                               int nbx, int nby, int K, int klen,
                                               int ldc)
{
  constexpr int NW  = TPB / 64;
  constexpr int RPW = 2 * BM / NW;
  constexpr int RI  = RPW / 16;
  constexpr int APW = BM * 64 / NW;
  constexpr int AIS = APW / 1024;
  constexpr int BPW = 8192 / NW;
  constexpr int BIS = BPW / 1024;
  __shared__ char sAh[2][BM * 64];
  __shared__ char sBh[2][8192];
  __shared__ char sBl[2][8192];
  const int tid = threadIdx.x, lane = tid & 63, w = tid >> 6;

  int nwg = gridDim.x, bid = blockIdx.x;
  int qq = nwg >> 3, rr = nwg & 7;
  int xc = bid & 7, ix = bid >> 3;
  int wg = (xc < rr ? xc * (qq + 1) : rr * (qq + 1) + (xc - rr) * qq) + ix;
  int bx = wg % nbx;
  int rem = wg / nbx;
  int by = rem % nby;
  int kbase = (rem / nby) * klen;

  const int m0 = by * BM, n0 = bx * 128;
  const int wm = (w >> 1) * RPW, wn = (w & 1) * 64;
  const int lhi = lane >> 4, llo = lane & 15;

  const f32x4 fz = {0.f, 0.f, 0.f, 0.f};
  f32x4 accH[RI][4], accM[RI][4];
#pragma unroll
  for (int i = 0; i < RI; ++i)
#pragma unroll
    for (int j = 0; j < 4; ++j) { accH[i][j] = fz; accM[i][j] = fz; }

  auto stage = [&](int buf, int k0) {
#pragma unroll
    for (int i = 0; i < AIS; ++i) {           // A plane
      int off = w * APW + i * 1024 + lane * 16;
      int r = off >> 6, c = (off >> 4) & 3;
      size_t go = (size_t)r * K + ((c ^ ((r >> 1) & 3)) << 3);
      GLD16(Ah + (size_t)m0 * K + k0 + go, &sAh[buf][w * APW + i * 1024]);
    }
#pragma unroll
    for (int i = 0; i < BIS; ++i) {           // B planes (hi+lo)
      int off = w * BPW + i * 1024 + lane * 16;
      int r = off >> 6, c = (off >> 4) & 3;
      size_t go = (size_t)r * K + ((c ^ ((r >> 1) & 3)) << 3);
      GLD16(Bh + (size_t)n0 * K + k0 + go, &sBh[buf][w * BPW + i * 1024]);
      GLD16(Bl + (size_t)n0 * K + k0 + go, &sBl[buf][w * BPW + i * 1024]);
    }
  };

  stage(0, kbase);
  asm volatile("s_waitcnt vmcnt(0)" ::: "memory");
  __builtin_amdgcn_s_barrier();

  int cur = 0;
  const int kend = kbase + klen;
  for (int k0 = kbase; k0 < kend; k0 += 32) {
    if (k0 + 32 < kend) stage(cur ^ 1, k0 + 32);

    f16x8 ah[RI], bh[4], bl[4];
#pragma unroll
    for (int r = 0; r < RI; ++r) {
      int ra = wm + r * 16 + llo;
      ah[r] = *(const f16x8*)(&sAh[cur][ra * 64 + ((lhi ^ ((ra >> 1) & 3)) << 4)]);
    }
#pragma unroll
    for (int r = 0; r < 4; ++r) {
      int rb = wn + r * 16 + llo;
      int sb = rb * 64 + ((lhi ^ ((rb >> 1) & 3)) << 4);
      bh[r] = *(const f16x8*)(&sBh[cur][sb]);
      bl[r] = *(const f16x8*)(&sBl[cur][sb]);
    }
#pragma unroll
    for (int i = 0; i < RI; ++i)
#pragma unroll
      for (int j = 0; j < 4; ++j) {
        accH[i][j] = __builtin_amdgcn_mfma_f32_16x16x32_f16(ah[i], bh[j], accH[i][j], 0, 0, 0);
        accM[i][j] = __builtin_amdgcn_mfma_f32_16x16x32_f16(ah[i], bl[j], accM[i][j], 0, 0, 0);
      }

    asm volatile("s_waitcnt vmcnt(0)" ::: "memory");
    __builtin_amdgcn_s_barrier();
    cur ^= 1;
  }

  if constexpr (MODE == 0) {
#pragma unroll
    for (int i = 0; i < RI; ++i)
#pragma unroll
      for (int j = 0; j < 4; ++j)
#pragma unroll
        for (int rg = 0; rg < 4; ++rg) {
          int m = m0 + wm + i * 16 + lhi * 4 + rg;
          int n = n0 + wn + j * 16 + llo;
          size_t idx = (size_t)m * ldc + n;
          float v = accH[i][j][rg] + accM[i][j][rg] * (1.0f / 1024.0f);
          if (R) v += R[idx];
          C[idx] = v;
        }
  } else if constexpr (MODE == 2) {
#pragma unroll
    for (int i = 0; i < RI; ++i)
#pragma unroll
      for (int j = 0; j < 4; ++j)
#pragma unroll
        for (int rg = 0; rg < 4; ++rg) {
          int m = m0 + wm + i * 16 + lhi * 4 + rg;
          int n = n0 + wn + j * 16 + llo;
          float v = accH[i][j][rg] + accM[i][j][rg] * (1.0f / 1024.0f);
          atomicAdd(&C[(size_t)m * ldc + n], v);
        }
  } else if constexpr (MODE == 1) {
#pragma unroll
    for (int i = 0; i < RI; ++i)
#pragma unroll
      for (int j = 0; j < 2; ++j)
#pragma unroll
        for (int rg = 0; rg < 4; ++rg) {
          int m = m0 + wm + i * 16 + lhi * 4 + rg;
          int n = (n0 >> 1) + (wn >> 1) + j * 16 + llo;
          float f1 = accH[i][j][rg]     + accM[i][j][rg]     * (1.0f / 1024.0f);
          float gv = accH[i][j + 2][rg] + accM[i][j + 2][rg] * (1.0f / 1024.0f);
          float y = f1 / (1.f + expf(-f1)) * gv;
          OH[(size_t)m * 3072 + n] = (_Float16)y;
        }
  } else {
    // MODE 3: fused qkvg epilogue (block-uniform region select on n0)
    if (n0 < 1536) {
      bool isq = n0 < 768;
      _Float16* dH = isq ? qH : kH;
      _Float16* dL = isq ? qL : kL;
      int nbase = isq ? n0 : n0 - 768;
#pragma unroll
      for (int i = 0; i < RI; ++i)
#pragma unroll
        for (int j = 0; j < 4; ++j) {
          int n = nbase + wn + j * 16 + llo;
          int h = n >> 6, idk = n & 63, jp = idk >> 1;
          float sgn = (n & 1) ? 1.f : -1.f;
#pragma unroll
          for (int rg = 0; rg < 4; ++rg) {
            int m = m0 + wm + i * 16 + lhi * 4 + rg;
            int s = m & (SEQ - 1), b = m >> 10;
            float v = accH[i][j][rg] + accM[i][j][rg] * (1.0f / 1024.0f);
            float p = __shfl_xor(v, 1);
            float cc = ct[s * 32 + jp], sn = st[s * 32 + jp];
            float r = v * cc + sgn * p * sn;
            _Float16 hh = (_Float16)r;
            size_t dst = ((size_t)(b * NH + h) * SEQ + s) * DKH + idk;
            dH[dst] = hh;
            dL[dst] = (_Float16)((r - (float)hh) * 1024.f);
          }
        }
    } else if (n0 < 3072) {
      int nbase = n0 - 1536;
#pragma unroll
      for (int i = 0; i < RI; ++i) {
        int m = m0 + wm + i * 16 + lhi * 4;
        int s = m & (SEQ - 1), b = m >> 10;
#pragma unroll
        for (int j = 0; j < 4; ++j) {
          int n = nbase + wn + j * 16 + llo;
          int h = n >> 7, d = n & 127;
          f16x4 tv;
#pragma unroll
          for (int rg = 0; rg < 4; ++rg)
            tv[rg] = (_Float16)(accH[i][j][rg] + accM[i][j][rg] * (1.0f / 1024.0f));
          *(f16x4*)(vtb + ((size_t)(b * NH + h) * DVH + d) * SEQ + s) = tv;
        }
      }
    } else {
      int nbase = n0 - 3072;
#pragma unroll
      for (int i = 0; i < RI; ++i)
#pragma unroll
        for (int j = 0; j < 4; ++j) {
          int n = nbase + wn + j * 16 + llo;
#pragma unroll
          for (int rg = 0; rg < 4; ++rg) {
            int m = m0 + wm + i * 16 + lhi * 4 + rg;
            float v = accH[i][j][rg] + accM[i][j][rg] * (1.0f / 1024.0f);
            gb[(size_t)m * DVAL + n] = (_Float16)v;
          }
        }
    }
  }
}

// =====================================================================
// retention stage 1: one block per (bh, rb): serial ct loop (1..8 tiles,
// lean inner: hoisted exp, no barriers), DIRECT coalesced stores — each
// q-row owned by exactly one block (no atomics, no memset).
// =====================================================================
__global__ __launch_bounds__(256) void attn_part(const _Float16* __restrict__ qrH_,
                                                 const _Float16* __restrict__ qrL_,
                                                 const _Float16* __restrict__ krH_,
                                                 const _Float16* __restrict__ krL_,
                                                 const _Float16* __restrict__ vt,
                                                 float* __restrict__ accb,
                                                 float* __restrict__ dsacc)
{
  __shared__ char pbuf[32768];          // 4 waves x [32][128] f16, XOR-swizzled
  const int tid = threadIdx.x, lane = tid & 63, w = tid >> 6;
  const int rb = blockIdx.x;            // row block 0..7
  const int bh = blockIdx.y;            // 0..47
  const int h = bh % NH;
  const int wrow0 = rb * 128 + w * 32;
  const int lhi = lane >> 4, llo = lane & 15;

  const _Float16* qbhH = qrH_ + (size_t)bh * SEQ * DKH;
  const _Float16* qbhL = qrL_ + (size_t)bh * SEQ * DKH;
  const _Float16* kbhH = krH_ + (size_t)bh * SEQ * DKH;
  const _Float16* kbhL = krL_ + (size_t)bh * SEQ * DKH;
  const _Float16* vbh  = vt   + (size_t)bh * DVH * SEQ;

  const float lg = log1pf(-exp2f(-(float)(5 + h)));   // ln(gamma_h)
  const float den_lg = expm1f(lg);                    // gamma - 1

  float invn[2][4];
#pragma unroll
  for (int rf = 0; rf < 2; ++rf)
#pragma unroll
    for (int rg = 0; rg < 4; ++rg) {
      int n = wrow0 + rf * 16 + lhi * 4 + rg;
      float sumD = expm1f((float)(n + 1) * lg) / den_lg;  // (1-g^{n+1})/(1-g)
      invn[rf][rg] = rsqrtf(sumD) * 0.125f;               // fold DK^-0.5
    }

  float gm[8];
#pragma unroll
  for (int fc = 0; fc < 8; ++fc)
    gm[fc] = expf(-(float)(fc * 16 + llo) * lg);

  f16x8 qaH[2][2], qaL[2][2];
#pragma unroll
  for (int rf = 0; rf < 2; ++rf)
#pragma unroll
    for (int kt = 0; kt < 2; ++kt) {
      size_t qo = (size_t)(wrow0 + rf * 16 + llo) * DKH + kt * 32 + lhi * 8;
      qaH[rf][kt] = *(const f16x8*)(qbhH + qo);
      qaL[rf][kt] = *(const f16x8*)(qbhL + qo);
    }

  const f32x4 fz = {0.f, 0.f, 0.f, 0.f};
  f32x4 acc[2][8];
#pragma unroll
  for (int i = 0; i < 2; ++i)
#pragma unroll
    for (int j = 0; j < 8; ++j) acc[i][j] = fz;
  float dsum[2][4] = {{0, 0, 0, 0}, {0, 0, 0, 0}};

  for (int ctc = 0; ctc <= rb; ++ctc) {
    const bool diag = (ctc == rb);
    float fn[2][4];
#pragma unroll
    for (int rf = 0; rf < 2; ++rf)
#pragma unroll
      for (int rg = 0; rg < 4; ++rg) {
        int n = wrow0 + rf * 16 + lhi * 4 + rg;
        fn[rf][rg] = expf((float)(n - ctc * 128) * lg) * invn[rf][rg];
      }

#pragma unroll
    for (int fc = 0; fc < 8; ++fc) {
      f32x4 pH[2] = {fz, fz}, pM[2] = {fz, fz};
#pragma unroll
      for (int kt = 0; kt < 2; ++kt) {
        size_t kro = (size_t)(ctc * 128 + fc * 16 + llo) * DKH + kt * 32 + lhi * 8;
        f16x8 kbH = *(const f16x8*)(kbhH + kro);
        f16x8 kbL = *(const f16x8*)(kbhL + kro);
        pH[0] = __builtin_amdgcn_mfma_f32_16x16x32_f16(qaH[0][kt], kbH, pH[0], 0, 0, 0);
        pH[1] = __builtin_amdgcn_mfma_f32_16x16x32_f16(qaH[1][kt], kbH, pH[1], 0, 0, 0);
        pM[0] = __builtin_amdgcn_mfma_f32_16x16x32_f16(qaL[0][kt], kbH, pM[0], 0, 0, 0);
        pM[1] = __builtin_amdgcn_mfma_f32_16x16x32_f16(qaL[1][kt], kbH, pM[1], 0, 0, 0);
        pM[0] = __builtin_amdgcn_mfma_f32_16x16x32_f16(qaH[0][kt], kbL, pM[0], 0, 0, 0);
        pM[1] = __builtin_amdgcn_mfma_f32_16x16x32_f16(qaH[1][kt], kbL, pM[1], 0, 0, 0);
      }
#pragma unroll
      for (int rf = 0; rf < 2; ++rf)
#pragma unroll
        for (int rg = 0; rg < 4; ++rg) {
          float pv = (pH[rf][rg] + pM[rf][rg] * (1.f / 1024.f)) * fn[rf][rg] * gm[fc];
          if (diag) {
            int e = (wrow0 + rf * 16 + lhi * 4 + rg) - (ctc * 128 + fc * 16 + llo);
            if (e < 0) pv = 0.f;
          }
          dsum[rf][rg] += fabsf(pv);
          int prow = rf * 16 + lhi * 4 + rg;
          int byte = (w << 13) + prow * 256 + (fc * 16 + llo) * 2;
          byte ^= (prow & 7) << 4;
          *(_Float16*)(pbuf + byte) = (_Float16)pv;
        }
    }
    // each wave reads only its own pbuf slice — no barrier needed

    f16x8 pa[2][4];
#pragma unroll
    for (int rf2 = 0; rf2 < 2; ++rf2)
#pragma unroll
      for (int kt = 0; kt < 4; ++kt) {
        int prow = rf2 * 16 + llo;
        int byte = (w << 13) + prow * 256 + kt * 64 + lhi * 16;
        byte ^= (prow & 7) << 4;
        pa[rf2][kt] = *(const f16x8*)(pbuf + byte);
      }
#pragma unroll
    for (int fd = 0; fd < 8; ++fd)
#pragma unroll
      for (int kt = 0; kt < 4; ++kt) {
        f16x8 vb = *(const f16x8*)(vbh + (size_t)(fd * 16 + llo) * SEQ + ctc * 128 + kt * 32 + lhi * 8);
        acc[0][fd] = __builtin_amdgcn_mfma_f32_16x16x32_f16(pa[0][kt], vb, acc[0][fd], 0, 0, 0);
        acc[1][fd] = __builtin_amdgcn_mfma_f32_16x16x32_f16(pa[1][kt], vb, acc[1][fd], 0, 0, 0);
      }
  }

  // ---- direct flush (each row owned by exactly this block) ----
  float* ab = accb + (size_t)bh * SEQ * DVH;
#pragma unroll
  for (int rf = 0; rf < 2; ++rf)
#pragma unroll
    for (int rg = 0; rg < 4; ++rg) {
      float d = dsum[rf][rg];
      d += __shfl_xor(d, 1); d += __shfl_xor(d, 2);
      d += __shfl_xor(d, 4); d += __shfl_xor(d, 8);
      int row = wrow0 + rf * 16 + lhi * 4 + rg;
      if (llo == 0) dsacc[bh * SEQ + row] = d;
#pragma unroll
      for (int fd = 0; fd < 8; ++fd)
        ab[(size_t)row * DVH + fd * 16 + llo] = acc[rf][fd][rg];
    }
}

// =====================================================================
// retention stage 2: row-normalize + group-norm + silu(g)*o fused,
// g read as f16 dense [row][1536]; writes ogb f16 [B*S][1536]
// =====================================================================
__global__ __launch_bounds__(256) void attn_norm(const float* __restrict__ accb,
                                                 const float* __restrict__ dsacc,
                                                 const _Float16* __restrict__ gsrc,
                                                 _Float16* __restrict__ oh)
{
  int bh = blockIdx.y, h = bh % NH, b = bh / NH;
  int s0 = blockIdx.x * 32;
  int lane = threadIdx.x & 63, w = threadIdx.x >> 6;
  const float* ab = accb + ((size_t)bh * SEQ + s0) * DVH;
#pragma unroll
  for (int i = 0; i < 8; ++i) {
    int r = w * 8 + i;
    size_t row = (size_t)(b * SEQ + s0 + r);
    float2 v = *(const float2*)(ab + (size_t)r * DVH + lane * 2);
    float inv = 1.f / fmaxf(dsacc[bh * SEQ + s0 + r], 1.f);
    v.x *= inv; v.y *= inv;
    float ss = v.x * v.x + v.y * v.y;
#pragma unroll
    for (int m = 1; m < 64; m <<= 1) ss += __shfl_xor(ss, m);
    float rs = rsqrtf(ss * (1.f / 128.f) + 1e-5f);
    float o0 = v.x * rs, o1 = v.y * rs;
    f16x2 gg = *(const f16x2*)(gsrc + row * DVAL + h * DVH + lane * 2);
    float gx = (float)gg[0], gy = (float)gg[1];
    float y0 = gx / (1.f + expf(-gx)) * o0;
    float y1 = gy / (1.f + expf(-gy)) * o1;
    f16x2 vh = {(_Float16)y0, (_Float16)y1};
    *(f16x2*)(oh + row * DVAL + h * DVH + lane * 2) = vh;
  }
}

// =====================================================================
// mean pool over S
// =====================================================================
__global__ void pool_kernel(const float* __restrict__ xf, float* __restrict__ pooled)
{
  int d = blockIdx.x * 256 + threadIdx.x;   // grid.x = 3
  int b = blockIdx.y;
  float acc = 0.f;
  for (int s = 0; s < SEQ; ++s) acc += xf[((size_t)(b * SEQ + s)) * DMOD + d];
  pooled[b * DMOD + d] = acc * (1.f / SEQ);
}

// =====================================================================
// classifier
// =====================================================================
__global__ void clf_kernel(const float* __restrict__ pooled, const float* __restrict__ cw,
                           const float* __restrict__ cb, float* __restrict__ out)
{
  int b = blockIdx.x, c = threadIdx.x;
  if (c < 100) {
    float acc = cb[c];
    for (int d = 0; d < DMOD; ++d) acc += pooled[b * DMOD + d] * cw[d * 100 + c];
    out[b * 100 + c] = acc;
  }
}

// =====================================================================
// host
// =====================================================================
extern "C" void kernel_launch(void* const* d_in, const int* in_sizes, int n_in,
                              void* d_out, int out_size, void* d_ws, size_t ws_size,
                              hipStream_t stream)
{
  const int*   ids  = (const int*)d_in[0];
  const float* emb  = (const float*)d_in[1];
  const float* wq   = (const float*)d_in[2];
  const float* wk   = (const float*)d_in[3];
  const float* wv   = (const float*)d_in[4];
  const float* wg   = (const float*)d_in[5];
  const float* wo   = (const float*)d_in[6];
  const float* ln1g = (const float*)d_in[7];
  const float* ln1b = (const float*)d_in[8];
  const float* ln2g = (const float*)d_in[9];
  const float* ln2b = (const float*)d_in[10];
  const float* fc1  = (const float*)d_in[11];
  const float* gate = (const float*)d_in[12];
  const float* fc2  = (const float*)d_in[13];
  const float* lnfg = (const float*)d_in[14];
  const float* lnfb = (const float*)d_in[15];
  const float* clfw = (const float*)d_in[16];
  const float* clfb = (const float*)d_in[17];
  float* out = (float*)d_out;

  char* ws = (char*)d_ws;
  size_t off = 0;
  auto alloc = [&](size_t bytes) {
    size_t r = off;
    off = (off + bytes + 255) & ~(size_t)255;
    return r;
  };

  const size_t W_QKVG = 12ull * 4608 * 768 * 2;
  const size_t W_O    = 12ull * 768 * 1536 * 2;
  const size_t W_F1GT = 12ull * 6144 * 768 * 2;
  const size_t W_F2   = 12ull * 768 * 3072 * 2;
  const bool big = ws_size >= 720ull * 1024 * 1024;
  const size_t d12 = big ? 1 : 12;

  _Float16* wQKVGh = (_Float16*)(ws + alloc(W_QKVG / d12));
  _Float16* wQKVGl = (_Float16*)(ws + alloc(W_QKVG / d12));
  _Float16* wOh    = (_Float16*)(ws + alloc(W_O    / d12));
  _Float16* wOl    = (_Float16*)(ws + alloc(W_O    / d12));
  _Float16* wF1GTh = (_Float16*)(ws + alloc(W_F1GT / d12));
  _Float16* wF1GTl = (_Float16*)(ws + alloc(W_F1GT / d12));
  _Float16* wF2h   = (_Float16*)(ws + alloc(W_F2   / d12));
  _Float16* wF2l   = (_Float16*)(ws + alloc(W_F2   / d12));

  float*    x    = (float*)(ws + alloc((size_t)BS * DMOD * 4));
  _Float16* hbfH = (_Float16*)(ws + alloc((size_t)BS * DMOD * 2));
  float*    cbuf = (float*)(ws + alloc((size_t)BS * DMOD * 4));   // final-LN scratch
  char*     regB = ws + alloc(8ull * 6291456);                    // 50.3 MB
  float*    accb = (float*)(ws + alloc((size_t)BS * DVAL * 4 + 48ull * SEQ * 4));
  float*    dsacc = accb + (size_t)BS * DVAL;
  float*    ctab = (float*)(ws + alloc(1024 * 32 * 4));
  float*    stab = (float*)(ws + alloc(1024 * 32 * 4));
  float*    pooled = (float*)(ws + alloc(4 * DMOD * 4));

  _Float16* qrbH = (_Float16*)regB;
  _Float16* qrbL = (_Float16*)(regB + 6291456);
  _Float16* krbH = (_Float16*)(regB + 12582912);
  _Float16* krbL = (_Float16*)(regB + 18874368);
  _Float16* vtb  = (_Float16*)(regB + 25165824);
  _Float16* gbuf = (_Float16*)(regB + 37748736);    // 12.58 MB, after vtb
  _Float16* ogbH = (_Float16*)regB;                 // alias (post-attn_part)
  _Float16* ffnbH = (_Float16*)regB;                // alias (post-wo)

  dim3 tb(32, 8);
  const long lsDD = 768l * 768, lsDV = 768l * 1536, lsDF = 768l * 3072;
  const long oQKVG = 4608l * 768, oO = 768l * 1536, oF1 = 6144l * 768, oF2 = 768l * 3072;

  trig_kernel<<<1024, 32, 0, stream>>>(ctab, stab);

  if (big) {
    wcvt_kernel<<<dim3(24, 24, 12), tb, 0, stream>>>(wq,   wQKVGh, wQKVGl, 768, 768,  lsDD, oQKVG, 0,    0);
    wcvt_kernel<<<dim3(24, 24, 12), tb, 0, stream>>>(wk,   wQKVGh, wQKVGl, 768, 768,  lsDD, oQKVG, 768,  0);
    wcvt_kernel<<<dim3(48, 24, 12), tb, 0, stream>>>(wv,   wQKVGh, wQKVGl, 768, 1536, lsDV, oQKVG, 1536, 0);
    wcvt_kernel<<<dim3(48, 24, 12), tb, 0, stream>>>(wg,   wQKVGh, wQKVGl, 768, 1536, lsDV, oQKVG, 3072, 0);
    wcvt_kernel<<<dim3(24, 48, 12), tb, 0, stream>>>(wo,   wOh,    wOl,    1536, 768, lsDV, oO,    0,    0);
    wcvt_kernel<<<dim3(96, 24, 12), tb, 0, stream>>>(fc1,  wF1GTh, wF1GTl, 768, 3072, lsDF, oF1,   0,    1);
    wcvt_kernel<<<dim3(96, 24, 12), tb, 0, stream>>>(gate, wF1GTh, wF1GTl, 768, 3072, lsDF, oF1,   0,    2);
    wcvt_kernel<<<dim3(24, 96, 12), tb, 0, stream>>>(fc2,  wF2h,   wF2l,   3072, 768, lsDF, oF2,   0,    0);
  }

  embed_kernel<<<BS, 192, 0, stream>>>(ids, emb, x);

  for (int l = 0; l < 12; ++l) {
    const _Float16 *Wqkh, *Wqkl, *Woh_, *Wol_, *Wfh, *Wfl, *W2h, *W2l;
    if (big) {
      Wqkh = wQKVGh + (size_t)l * oQKVG;  Wqkl = wQKVGl + (size_t)l * oQKVG;
      Woh_ = wOh    + (size_t)l * oO;     Wol_ = wOl    + (size_t)l * oO;
      Wfh  = wF1GTh + (size_t)l * oF1;    Wfl  = wF1GTl + (size_t)l * oF1;
      W2h  = wF2h   + (size_t)l * oF2;    W2l  = wF2l   + (size_t)l * oF2;
    } else {
      wcvt_kernel<<<dim3(24, 24, 1), tb, 0, stream>>>(wq   + (size_t)l * lsDD, wQKVGh, wQKVGl, 768, 768,  0, 0, 0,    0);
      wcvt_kernel<<<dim3(24, 24, 1), tb, 0, stream>>>(wk   + (size_t)l * lsDD, wQKVGh, wQKVGl, 768, 768,  0, 0, 768,  0);
      wcvt_kernel<<<dim3(48, 24, 1), tb, 0, stream>>>(wv   + (size_t)l * lsDV, wQKVGh, wQKVGl, 768, 1536, 0, 0, 1536, 0);
      wcvt_kernel<<<dim3(48, 24, 1), tb, 0, stream>>>(wg   + (size_t)l * lsDV, wQKVGh, wQKVGl, 768, 1536, 0, 0, 3072, 0);
      wcvt_kernel<<<dim3(24, 48, 1), tb, 0, stream>>>(wo   + (size_t)l * lsDV, wOh,    wOl,    1536, 768, 0, 0, 0,    0);
      wcvt_kernel<<<dim3(96, 24, 1), tb, 0, stream>>>(fc1  + (size_t)l * lsDF, wF1GTh, wF1GTl, 768, 3072, 0, 0, 0,    1);
      wcvt_kernel<<<dim3(96, 24, 1), tb, 0, stream>>>(gate + (size_t)l * lsDF, wF1GTh, wF1GTl, 768, 3072, 0, 0, 0,    2);
      wcvt_kernel<<<dim3(24, 96, 1), tb, 0, stream>>>(fc2  + (size_t)l * lsDF, wF2h,   wF2l,   3072, 768, 0, 0, 0,    0);
      Wqkh = wQKVGh; Wqkl = wQKVGl; Woh_ = wOh; Wol_ = wOl;
      Wfh = wF1GTh; Wfl = wF1GTl; W2h = wF2h; W2l = wF2l;
    }

    ln_h_kernel<<<BS, 256, 0, stream>>>(x, ln1g + l * 768, ln1b + l * 768, hbfH);
    // fused qkvg: 256x128 tile, 8 waves
    gemm_bt<256, 3, 512><<<36 * 16, 512, 0, stream>>>(hbfH, Wqkh, Wqkl, nullptr, nullptr,
                                                      nullptr, qrbH, qrbL, krbH, krbL,
                                                      vtb, gbuf, ctab, stab,
                                                      36, 16, 768, 768, 0);
    attn_part<<<dim3(8, 48), 256, 0, stream>>>(qrbH, qrbL, krbH, krbL, vtb, accb, dsacc);
    attn_norm<<<dim3(32, 48), 256, 0, stream>>>(accb, dsacc, gbuf, ogbH);
    // wo: split-K x2, partials atomically accumulate into x (holds residual)
    gemm_bt<64, 2, 256><<<6 * 64 * 2, 256, 0, stream>>>(ogbH, Woh_, Wol_, x, nullptr,
                                                        nullptr, nullptr, nullptr, nullptr,
                                                        nullptr, nullptr, nullptr, nullptr,
                                                        nullptr, 6, 64, 1536, 768, 768);
    ln_h_kernel<<<BS, 256, 0, stream>>>(x, ln2g + l * 768, ln2b + l * 768, hbfH);
    // f1gt: 256x128 tile, 8 waves, fused silu-gate epilogue
    gemm_bt<256, 1, 512><<<48 * 16, 512, 0, stream>>>(hbfH, Wfh, Wfl, nullptr, nullptr,
                                                      ffnbH, nullptr, nullptr, nullptr,
                                                      nullptr, nullptr, nullptr, nullptr,
                                                      nullptr, 48, 16, 768, 768, 0);
    // f2: split-K x4
    gemm_bt<64, 2, 256><<<6 * 64 * 4, 256, 0, stream>>>(ffnbH, W2h, W2l, x, nullptr,
                                                        nullptr, nullptr, nullptr, nullptr,
                                                        nullptr, nullptr, nullptr, nullptr,
                                                        nullptr, 6, 64, 3072, 768, 768);
  }

  float* xf = cbuf;
  ln_kernel<<<BS, 256, 0, stream>>>(x, lnfg, lnfb, xf);
  pool_kernel<<<dim3(3, 4), 256, 0, stream>>>(xf, pooled);
  clf_kernel<<<4, 128, 0, stream>>>(pooled, clfw, clfb, out);
}

// Round 19
// 6203.968 us; speedup vs baseline: 1.1292x; 1.1292x over previous
//
#include <hip/hip_runtime.h>
#include <cstdint>
#include <cstddef>

// ---------- types ----------
typedef float     f32x4 __attribute__((ext_vector_type(4)));
typedef _Float16  f16x8 __attribute__((ext_vector_type(8)));
typedef _Float16  f16x4 __attribute__((ext_vector_type(4)));
typedef _Float16  f16x2 __attribute__((ext_vector_type(2)));

#define GLD16(g, l)                                                            \
  __builtin_amdgcn_global_load_lds(                                           \
      (const __attribute__((address_space(1))) void*)(g),                     \
      (__attribute__((address_space(3))) void*)(l), 16, 0, 0)

// ---------- constants ----------
#define BQ    4
#define SEQ   1024
#define DMOD  768
#define NH    12
#define DKH   64
#define DVH   128
#define DVAL  1536
#define DFFN  3072
#define BS    4096   /* BQ*SEQ */

// =====================================================================
// theta-shift trig table: ct/st[s][jp], jp=0..31
// =====================================================================
__global__ void trig_kernel(float* __restrict__ ct, float* __restrict__ st)
{
  int s = blockIdx.x, jp = threadIdx.x;   // 1024 x 32
  float ang = exp2f(-(float)jp * (13.287712379549449f / 31.f));
  float a = (float)s * ang;
  ct[s * 32 + jp] = cosf(a);
  st[s * 32 + jp] = sinf(a);
}

// =====================================================================
// weight transpose + f32->f16 hi/lo split into fused layout.
// mode 0: orow = row_off + n  (linear)
// mode 1: fc1 interleave : orow = (n>>6)*128 + ((n>>5)&1)*64 + (n&31)
// mode 2: gate interleave: orow = (n>>6)*128 + ((n>>5)&1)*64 + 32 + (n&31)
// =====================================================================
__global__ void wcvt_kernel(const float* __restrict__ win, _Float16* __restrict__ whi,
                            _Float16* __restrict__ wlo, int K, int N,
                            long in_ls, long out_ls, int row_off, int mode)
{
  __shared__ float tle[32][33];
  size_t ib = (size_t)blockIdx.z * in_ls;
  size_t ob = (size_t)blockIdx.z * out_ls;
  int k0 = blockIdx.y * 32, n0 = blockIdx.x * 32;
  int tx = threadIdx.x, ty = threadIdx.y;
#pragma unroll
  for (int i = 0; i < 4; ++i)
    tle[ty + 8*i][tx] = win[ib + (size_t)(k0 + ty + 8*i) * N + n0 + tx];
  __syncthreads();
#pragma unroll
  for (int i = 0; i < 4; ++i) {
    float v = tle[tx][ty + 8*i];
    _Float16 h = (_Float16)v;
    int n = n0 + ty + 8*i;
    int orow;
    if (mode == 0)      orow = row_off + n;
    else if (mode == 1) orow = (n >> 6) * 128 + ((n >> 5) & 1) * 64 + (n & 31);
    else                orow = (n >> 6) * 128 + ((n >> 5) & 1) * 64 + 32 + (n & 31);
    size_t idx = ob + (size_t)orow * K + k0 + tx;
    whi[idx] = h;
    wlo[idx] = (_Float16)((v - (float)h) * 1024.0f);
  }
}

// =====================================================================
// embedding gather
// =====================================================================
__global__ void embed_kernel(const int* __restrict__ ids, const float* __restrict__ emb,
                             float* __restrict__ x)
{
  int tok = blockIdx.x;
  int id  = ids[tok];
  const float4* s = (const float4*)(emb + (size_t)id * DMOD);
  float4*       d = (float4*)(x + (size_t)tok * DMOD);
  d[threadIdx.x] = s[threadIdx.x];   // block = 192 threads
}

// =====================================================================
// layernorm over 768 -> f32 out (final LN)
// =====================================================================
__global__ __launch_bounds__(256) void ln_kernel(const float* __restrict__ x,
                                                 const float* __restrict__ g,
                                                 const float* __restrict__ bta,
                                                 float* __restrict__ out)
{
  int row = blockIdx.x;
  const float* xr = x + (size_t)row * DMOD;
  int t = threadIdx.x;
  float v0 = xr[t], v1 = xr[t + 256], v2 = xr[t + 512];
  float s  = v0 + v1 + v2;
  float sq = v0*v0 + v1*v1 + v2*v2;
#pragma unroll
  for (int m = 1; m < 64; m <<= 1) { s += __shfl_xor(s, m); sq += __shfl_xor(sq, m); }
  __shared__ float red[8];
  int wv = t >> 6, ln_ = t & 63;
  if (ln_ == 0) { red[wv] = s; red[wv + 4] = sq; }
  __syncthreads();
  s  = red[0] + red[1] + red[2] + red[3];
  sq = red[4] + red[5] + red[6] + red[7];
  float mu = s * (1.f / DMOD);
  float rs = rsqrtf(sq * (1.f / DMOD) - mu * mu + 1e-5f);
  out[(size_t)row * DMOD + t      ] = (v0 - mu) * rs * g[t      ] + bta[t      ];
  out[(size_t)row * DMOD + t + 256] = (v1 - mu) * rs * g[t + 256] + bta[t + 256];
  out[(size_t)row * DMOD + t + 512] = (v2 - mu) * rs * g[t + 512] + bta[t + 512];
}

// =====================================================================
// layernorm over 768 -> f16 (GEMM A-operand)
// =====================================================================
__global__ __launch_bounds__(256) void ln_h_kernel(const float* __restrict__ x,
                                                   const float* __restrict__ g,
                                                   const float* __restrict__ bta,
                                                   _Float16* __restrict__ oh)
{
  int row = blockIdx.x;
  const float* xr = x + (size_t)row * DMOD;
  int t = threadIdx.x;
  float v0 = xr[t], v1 = xr[t + 256], v2 = xr[t + 512];
  float s  = v0 + v1 + v2;
  float sq = v0*v0 + v1*v1 + v2*v2;
#pragma unroll
  for (int m = 1; m < 64; m <<= 1) { s += __shfl_xor(s, m); sq += __shfl_xor(sq, m); }
  __shared__ float red[8];
  int wv = t >> 6, ln_ = t & 63;
  if (ln_ == 0) { red[wv] = s; red[wv + 4] = sq; }
  __syncthreads();
  s  = red[0] + red[1] + red[2] + red[3];
  sq = red[4] + red[5] + red[6] + red[7];
  float mu = s * (1.f / DMOD);
  float rs = rsqrtf(sq * (1.f / DMOD) - mu * mu + 1e-5f);
#pragma unroll
  for (int q = 0; q < 3; ++q) {
    int c = t + q * 256;
    float y = (xr[c] - mu) * rs * g[c] + bta[c];
    oh[(size_t)row * DMOD + c] = (_Float16)y;
  }
}

// =====================================================================
// GEMM: A[M][K](f16) @ (Bh + Bl/1024)[NTOT][K](f16)^T, 2-term split.
// BM x 128 tile, BK=32, TPB/64 waves, global_load_lds, XCD swizzle,
// N-fastest traversal, 2-buffer pipeline, conflict-free LDS swizzle.
// MODE 0: C f32 (opt += R).  MODE 1: silu-gate f16.  MODE 2: split-K
// atomic.  MODE 3: fused qkvg epilogue.
// =====================================================================
template<int BM, int MODE, int TPB>
__global__ __launch_bounds__(TPB) void gemm_bt(const _Float16* __restrict__ Ah,
                                               const _Float16* __restrict__ Bh,
                                               const _Float16* __restrict__ Bl,
                                               float* __restrict__ C,
                                               const float* __restrict__ R,
                                               _Float16* __restrict__ OH,
                                               _Float16* __restrict__ qH,
                                               _Float16* __restrict__ qL,
                                               _Float16* __restrict__ kH,
                                               _Float16* __restrict__ kL,
                                               _Float16* __restrict__ vtb,
                                               _Float16* __restrict__ gb,
                                               const float* __restrict__ ct,
                                               const float* __restrict__ st,
                                               int nbx, int nby, int K, int klen,
                                               int ldc)
{
  constexpr int NW  = TPB / 64;
  constexpr int RPW = 2 * BM / NW;
  constexpr int RI  = RPW / 16;
  constexpr int APW = BM * 64 / NW;
  constexpr int AIS = APW / 1024;
  constexpr int BPW = 8192 / NW;
  constexpr int BIS = BPW / 1024;
  __shared__ char sAh[2][BM * 64];
  __shared__ char sBh[2][8192];
  __shared__ char sBl[2][8192];
  const int tid = threadIdx.x, lane = tid & 63, w = tid >> 6;

  int nwg = gridDim.x, bid = blockIdx.x;
  int qq = nwg >> 3, rr = nwg & 7;
  int xc = bid & 7, ix = bid >> 3;
  int wg = (xc < rr ? xc * (qq + 1) : rr * (qq + 1) + (xc - rr) * qq) + ix;
  int bx = wg % nbx;
  int rem = wg / nbx;
  int by = rem % nby;
  int kbase = (rem / nby) * klen;

  const int m0 = by * BM, n0 = bx * 128;
  const int wm = (w >> 1) * RPW, wn = (w & 1) * 64;
  const int lhi = lane >> 4, llo = lane & 15;

  const f32x4 fz = {0.f, 0.f, 0.f, 0.f};
  f32x4 accH[RI][4], accM[RI][4];
#pragma unroll
  for (int i = 0; i < RI; ++i)
#pragma unroll
    for (int j = 0; j < 4; ++j) { accH[i][j] = fz; accM[i][j] = fz; }

  auto stage = [&](int buf, int k0) {
#pragma unroll
    for (int i = 0; i < AIS; ++i) {           // A plane
      int off = w * APW + i * 1024 + lane * 16;
      int r = off >> 6, c = (off >> 4) & 3;
      size_t go = (size_t)r * K + ((c ^ ((r >> 1) & 3)) << 3);
      GLD16(Ah + (size_t)m0 * K + k0 + go, &sAh[buf][w * APW + i * 1024]);
    }
#pragma unroll
    for (int i = 0; i < BIS; ++i) {           // B planes (hi+lo)
      int off = w * BPW + i * 1024 + lane * 16;
      int r = off >> 6, c = (off >> 4) & 3;
      size_t go = (size_t)r * K + ((c ^ ((r >> 1) & 3)) << 3);
      GLD16(Bh + (size_t)n0 * K + k0 + go, &sBh[buf][w * BPW + i * 1024]);
      GLD16(Bl + (size_t)n0 * K + k0 + go, &sBl[buf][w * BPW + i * 1024]);
    }
  };

  stage(0, kbase);
  asm volatile("s_waitcnt vmcnt(0)" ::: "memory");
  __builtin_amdgcn_s_barrier();

  int cur = 0;
  const int kend = kbase + klen;
  for (int k0 = kbase; k0 < kend; k0 += 32) {
    if (k0 + 32 < kend) stage(cur ^ 1, k0 + 32);

    f16x8 ah[RI], bh[4], bl[4];
#pragma unroll
    for (int r = 0; r < RI; ++r) {
      int ra = wm + r * 16 + llo;
      ah[r] = *(const f16x8*)(&sAh[cur][ra * 64 + ((lhi ^ ((ra >> 1) & 3)) << 4)]);
    }
#pragma unroll
    for (int r = 0; r < 4; ++r) {
      int rb = wn + r * 16 + llo;
      int sb = rb * 64 + ((lhi ^ ((rb >> 1) & 3)) << 4);
      bh[r] = *(const f16x8*)(&sBh[cur][sb]);
      bl[r] = *(const f16x8*)(&sBl[cur][sb]);
    }
#pragma unroll
    for (int i = 0; i < RI; ++i)
#pragma unroll
      for (int j = 0; j < 4; ++j) {
        accH[i][j] = __builtin_amdgcn_mfma_f32_16x16x32_f16(ah[i], bh[j], accH[i][j], 0, 0, 0);
        accM[i][j] = __builtin_amdgcn_mfma_f32_16x16x32_f16(ah[i], bl[j], accM[i][j], 0, 0, 0);
      }

    asm volatile("s_waitcnt vmcnt(0)" ::: "memory");
    __builtin_amdgcn_s_barrier();
    cur ^= 1;
  }

  if constexpr (MODE == 0) {
#pragma unroll
    for (int i = 0; i < RI; ++i)
#pragma unroll
      for (int j = 0; j < 4; ++j)
#pragma unroll
        for (int rg = 0; rg < 4; ++rg) {
          int m = m0 + wm + i * 16 + lhi * 4 + rg;
          int n = n0 + wn + j * 16 + llo;
          size_t idx = (size_t)m * ldc + n;
          float v = accH[i][j][rg] + accM[i][j][rg] * (1.0f / 1024.0f);
          if (R) v += R[idx];
          C[idx] = v;
        }
  } else if constexpr (MODE == 2) {
#pragma unroll
    for (int i = 0; i < RI; ++i)
#pragma unroll
      for (int j = 0; j < 4; ++j)
#pragma unroll
        for (int rg = 0; rg < 4; ++rg) {
          int m = m0 + wm + i * 16 + lhi * 4 + rg;
          int n = n0 + wn + j * 16 + llo;
          float v = accH[i][j][rg] + accM[i][j][rg] * (1.0f / 1024.0f);
          atomicAdd(&C[(size_t)m * ldc + n], v);
        }
  } else if constexpr (MODE == 1) {
#pragma unroll
    for (int i = 0; i < RI; ++i)
#pragma unroll
      for (int j = 0; j < 2; ++j)
#pragma unroll
        for (int rg = 0; rg < 4; ++rg) {
          int m = m0 + wm + i * 16 + lhi * 4 + rg;
          int n = (n0 >> 1) + (wn >> 1) + j * 16 + llo;
          float f1 = accH[i][j][rg]     + accM[i][j][rg]     * (1.0f / 1024.0f);
          float gv = accH[i][j + 2][rg] + accM[i][j + 2][rg] * (1.0f / 1024.0f);
          float y = f1 / (1.f + expf(-f1)) * gv;
          OH[(size_t)m * 3072 + n] = (_Float16)y;
        }
  } else {
    // MODE 3: fused qkvg epilogue (block-uniform region select on n0)
    if (n0 < 1536) {
      bool isq = n0 < 768;
      _Float16* dH = isq ? qH : kH;
      _Float16* dL = isq ? qL : kL;
      int nbase = isq ? n0 : n0 - 768;
#pragma unroll
      for (int i = 0; i < RI; ++i)
#pragma unroll
        for (int j = 0; j < 4; ++j) {
          int n = nbase + wn + j * 16 + llo;
          int h = n >> 6, idk = n & 63, jp = idk >> 1;
          float sgn = (n & 1) ? 1.f : -1.f;
#pragma unroll
          for (int rg = 0; rg < 4; ++rg) {
            int m = m0 + wm + i * 16 + lhi * 4 + rg;
            int s = m & (SEQ - 1), b = m >> 10;
            float v = accH[i][j][rg] + accM[i][j][rg] * (1.0f / 1024.0f);
            float p = __shfl_xor(v, 1);
            float cc = ct[s * 32 + jp], sn = st[s * 32 + jp];
            float r = v * cc + sgn * p * sn;
            _Float16 hh = (_Float16)r;
            size_t dst = ((size_t)(b * NH + h) * SEQ + s) * DKH + idk;
            dH[dst] = hh;
            dL[dst] = (_Float16)((r - (float)hh) * 1024.f);
          }
        }
    } else if (n0 < 3072) {
      int nbase = n0 - 1536;
#pragma unroll
      for (int i = 0; i < RI; ++i) {
        int m = m0 + wm + i * 16 + lhi * 4;
        int s = m & (SEQ - 1), b = m >> 10;
#pragma unroll
        for (int j = 0; j < 4; ++j) {
          int n = nbase + wn + j * 16 + llo;
          int h = n >> 7, d = n & 127;
          f16x4 tv;
#pragma unroll
          for (int rg = 0; rg < 4; ++rg)
            tv[rg] = (_Float16)(accH[i][j][rg] + accM[i][j][rg] * (1.0f / 1024.0f));
          *(f16x4*)(vtb + ((size_t)(b * NH + h) * DVH + d) * SEQ + s) = tv;
        }
      }
    } else {
      int nbase = n0 - 3072;
#pragma unroll
      for (int i = 0; i < RI; ++i)
#pragma unroll
        for (int j = 0; j < 4; ++j) {
          int n = nbase + wn + j * 16 + llo;
#pragma unroll
          for (int rg = 0; rg < 4; ++rg) {
            int m = m0 + wm + i * 16 + lhi * 4 + rg;
            float v = accH[i][j][rg] + accM[i][j][rg] * (1.0f / 1024.0f);
            gb[(size_t)m * DVAL + n] = (_Float16)v;
          }
        }
    }
  }
}

// =====================================================================
// retention stage 1 (round-17 split-K form): per (bh, rb, ct-chunk<=2):
// QK^T(3-term) -> decay -> PV partial; atomicAdd into accbuf and dsacc.
// 960 uniform blocks — parallelism beats write thrift here (measured).
// =====================================================================
__global__ __launch_bounds__(256) void attn_part(const _Float16* __restrict__ qrH_,
                                                 const _Float16* __restrict__ qrL_,
                                                 const _Float16* __restrict__ krH_,
                                                 const _Float16* __restrict__ krL_,
                                                 const _Float16* __restrict__ vt,
                                                 float* __restrict__ accb,
                                                 float* __restrict__ dsacc)
{
  static const int RBtab[20] = {0,1,2,2,3,3,4,4,4,5,5,5,6,6,6,6,7,7,7,7};
  static const int C0tab[20] = {0,0,0,2,0,2,0,2,4,0,2,4,0,2,4,6,0,2,4,6};
  __shared__ char pbuf[32768];          // 4 waves x [32][128] f16, XOR-swizzled
  const int tid = threadIdx.x, lane = tid & 63, w = tid >> 6;
  const int rb = RBtab[blockIdx.x], c0 = C0tab[blockIdx.x];
  const int bh = blockIdx.y;            // 0..47
  const int h = bh % NH;
  const int wrow0 = rb * 128 + w * 32;
  const int lhi = lane >> 4, llo = lane & 15;

  const _Float16* qbhH = qrH_ + (size_t)bh * SEQ * DKH;
  const _Float16* qbhL = qrL_ + (size_t)bh * SEQ * DKH;
  const _Float16* kbhH = krH_ + (size_t)bh * SEQ * DKH;
  const _Float16* kbhL = krL_ + (size_t)bh * SEQ * DKH;
  const _Float16* vbh  = vt   + (size_t)bh * DVH * SEQ;

  const float lg = log1pf(-exp2f(-(float)(5 + h)));   // ln(gamma_h)
  const float den_lg = expm1f(lg);                    // gamma - 1

  float invn[2][4];
#pragma unroll
  for (int rf = 0; rf < 2; ++rf)
#pragma unroll
    for (int rg = 0; rg < 4; ++rg) {
      int n = wrow0 + rf * 16 + lhi * 4 + rg;
      float sumD = expm1f((float)(n + 1) * lg) / den_lg;  // (1-g^{n+1})/(1-g)
      invn[rf][rg] = rsqrtf(sumD) * 0.125f;               // fold DK^-0.5
    }

  float gm[8];
#pragma unroll
  for (int fc = 0; fc < 8; ++fc)
    gm[fc] = expf(-(float)(fc * 16 + llo) * lg);

  f16x8 qaH[2][2], qaL[2][2];
#pragma unroll
  for (int rf = 0; rf < 2; ++rf)
#pragma unroll
    for (int kt = 0; kt < 2; ++kt) {
      size_t qo = (size_t)(wrow0 + rf * 16 + llo) * DKH + kt * 32 + lhi * 8;
      qaH[rf][kt] = *(const f16x8*)(qbhH + qo);
      qaL[rf][kt] = *(const f16x8*)(qbhL + qo);
    }

  const f32x4 fz = {0.f, 0.f, 0.f, 0.f};
  f32x4 acc[2][8];
#pragma unroll
  for (int i = 0; i < 2; ++i)
#pragma unroll
    for (int j = 0; j < 8; ++j) acc[i][j] = fz;
  float dsum[2][4] = {{0, 0, 0, 0}, {0, 0, 0, 0}};

  const int ctend = (c0 + 1 < rb) ? c0 + 1 : rb;
  for (int ctc = c0; ctc <= ctend; ++ctc) {
    const bool diag = (ctc == rb);
    float fn[2][4];
#pragma unroll
    for (int rf = 0; rf < 2; ++rf)
#pragma unroll
      for (int rg = 0; rg < 4; ++rg) {
        int n = wrow0 + rf * 16 + lhi * 4 + rg;
        fn[rf][rg] = expf((float)(n - ctc * 128) * lg) * invn[rf][rg];
      }

#pragma unroll
    for (int fc = 0; fc < 8; ++fc) {
      f32x4 pH[2] = {fz, fz}, pM[2] = {fz, fz};
#pragma unroll
      for (int kt = 0; kt < 2; ++kt) {
        size_t kro = (size_t)(ctc * 128 + fc * 16 + llo) * DKH + kt * 32 + lhi * 8;
        f16x8 kbH = *(const f16x8*)(kbhH + kro);
        f16x8 kbL = *(const f16x8*)(kbhL + kro);
        pH[0] = __builtin_amdgcn_mfma_f32_16x16x32_f16(qaH[0][kt], kbH, pH[0], 0, 0, 0);
        pH[1] = __builtin_amdgcn_mfma_f32_16x16x32_f16(qaH[1][kt], kbH, pH[1], 0, 0, 0);
        pM[0] = __builtin_amdgcn_mfma_f32_16x16x32_f16(qaL[0][kt], kbH, pM[0], 0, 0, 0);
        pM[1] = __builtin_amdgcn_mfma_f32_16x16x32_f16(qaL[1][kt], kbH, pM[1], 0, 0, 0);
        pM[0] = __builtin_amdgcn_mfma_f32_16x16x32_f16(qaH[0][kt], kbL, pM[0], 0, 0, 0);
        pM[1] = __builtin_amdgcn_mfma_f32_16x16x32_f16(qaH[1][kt], kbL, pM[1], 0, 0, 0);
      }
#pragma unroll
      for (int rf = 0; rf < 2; ++rf)
#pragma unroll
        for (int rg = 0; rg < 4; ++rg) {
          float pv = (pH[rf][rg] + pM[rf][rg] * (1.f / 1024.f)) * fn[rf][rg] * gm[fc];
          if (diag) {
            int e = (wrow0 + rf * 16 + lhi * 4 + rg) - (ctc * 128 + fc * 16 + llo);
            if (e < 0) pv = 0.f;
          }
          dsum[rf][rg] += fabsf(pv);
          int prow = rf * 16 + lhi * 4 + rg;
          int byte = (w << 13) + prow * 256 + (fc * 16 + llo) * 2;
          byte ^= (prow & 7) << 4;
          *(_Float16*)(pbuf + byte) = (_Float16)pv;
        }
    }
    // each wave reads only its own pbuf slice — no barrier needed

    f16x8 pa[2][4];
#pragma unroll
    for (int rf2 = 0; rf2 < 2; ++rf2)
#pragma unroll
      for (int kt = 0; kt < 4; ++kt) {
        int prow = rf2 * 16 + llo;
        int byte = (w << 13) + prow * 256 + kt * 64 + lhi * 16;
        byte ^= (prow & 7) << 4;
        pa[rf2][kt] = *(const f16x8*)(pbuf + byte);
      }
#pragma unroll
    for (int fd = 0; fd < 8; ++fd)
#pragma unroll
      for (int kt = 0; kt < 4; ++kt) {
        f16x8 vb = *(const f16x8*)(vbh + (size_t)(fd * 16 + llo) * SEQ + ctc * 128 + kt * 32 + lhi * 8);
        acc[0][fd] = __builtin_amdgcn_mfma_f32_16x16x32_f16(pa[0][kt], vb, acc[0][fd], 0, 0, 0);
        acc[1][fd] = __builtin_amdgcn_mfma_f32_16x16x32_f16(pa[1][kt], vb, acc[1][fd], 0, 0, 0);
      }
  }

  float* ab = accb + (size_t)bh * SEQ * DVH;
#pragma unroll
  for (int rf = 0; rf < 2; ++rf)
#pragma unroll
    for (int rg = 0; rg < 4; ++rg) {
      float d = dsum[rf][rg];
      d += __shfl_xor(d, 1); d += __shfl_xor(d, 2);
      d += __shfl_xor(d, 4); d += __shfl_xor(d, 8);
      int row = wrow0 + rf * 16 + lhi * 4 + rg;
      if (llo == 0) atomicAdd(&dsacc[bh * SEQ + row], d);
#pragma unroll
      for (int fd = 0; fd < 8; ++fd)
        atomicAdd(&ab[(size_t)row * DVH + fd * 16 + llo], acc[rf][fd][rg]);
    }
}

// =====================================================================
// retention stage 2: row-normalize + group-norm + silu(g)*o fused,
// g read as f16 dense [row][1536]; writes ogb f16 [B*S][1536]
// =====================================================================
__global__ __launch_bounds__(256) void attn_norm(const float* __restrict__ accb,
                                                 const float* __restrict__ dsacc,
                                                 const _Float16* __restrict__ gsrc,
                                                 _Float16* __restrict__ oh)
{
  int bh = blockIdx.y, h = bh % NH, b = bh / NH;
  int s0 = blockIdx.x * 32;
  int lane = threadIdx.x & 63, w = threadIdx.x >> 6;
  const float* ab = accb + ((size_t)bh * SEQ + s0) * DVH;
#pragma unroll
  for (int i = 0; i < 8; ++i) {
    int r = w * 8 + i;
    size_t row = (size_t)(b * SEQ + s0 + r);
    float2 v = *(const float2*)(ab + (size_t)r * DVH + lane * 2);
    float inv = 1.f / fmaxf(dsacc[bh * SEQ + s0 + r], 1.f);
    v.x *= inv; v.y *= inv;
    float ss = v.x * v.x + v.y * v.y;
#pragma unroll
    for (int m = 1; m < 64; m <<= 1) ss += __shfl_xor(ss, m);
    float rs = rsqrtf(ss * (1.f / 128.f) + 1e-5f);
    float o0 = v.x * rs, o1 = v.y * rs;
    f16x2 gg = *(const f16x2*)(gsrc + row * DVAL + h * DVH + lane * 2);
    float gx = (float)gg[0], gy = (float)gg[1];
    float y0 = gx / (1.f + expf(-gx)) * o0;
    float y1 = gy / (1.f + expf(-gy)) * o1;
    f16x2 vh = {(_Float16)y0, (_Float16)y1};
    *(f16x2*)(oh + row * DVAL + h * DVH + lane * 2) = vh;
  }
}

// =====================================================================
// mean pool over S
// =====================================================================
__global__ void pool_kernel(const float* __restrict__ xf, float* __restrict__ pooled)
{
  int d = blockIdx.x * 256 + threadIdx.x;   // grid.x = 3
  int b = blockIdx.y;
  float acc = 0.f;
  for (int s = 0; s < SEQ; ++s) acc += xf[((size_t)(b * SEQ + s)) * DMOD + d];
  pooled[b * DMOD + d] = acc * (1.f / SEQ);
}

// =====================================================================
// classifier
// =====================================================================
__global__ void clf_kernel(const float* __restrict__ pooled, const float* __restrict__ cw,
                           const float* __restrict__ cb, float* __restrict__ out)
{
  int b = blockIdx.x, c = threadIdx.x;
  if (c < 100) {
    float acc = cb[c];
    for (int d = 0; d < DMOD; ++d) acc += pooled[b * DMOD + d] * cw[d * 100 + c];
    out[b * 100 + c] = acc;
  }
}

// =====================================================================
// host
// =====================================================================
extern "C" void kernel_launch(void* const* d_in, const int* in_sizes, int n_in,
                              void* d_out, int out_size, void* d_ws, size_t ws_size,
                              hipStream_t stream)
{
  const int*   ids  = (const int*)d_in[0];
  const float* emb  = (const float*)d_in[1];
  const float* wq   = (const float*)d_in[2];
  const float* wk   = (const float*)d_in[3];
  const float* wv   = (const float*)d_in[4];
  const float* wg   = (const float*)d_in[5];
  const float* wo   = (const float*)d_in[6];
  const float* ln1g = (const float*)d_in[7];
  const float* ln1b = (const float*)d_in[8];
  const float* ln2g = (const float*)d_in[9];
  const float* ln2b = (const float*)d_in[10];
  const float* fc1  = (const float*)d_in[11];
  const float* gate = (const float*)d_in[12];
  const float* fc2  = (const float*)d_in[13];
  const float* lnfg = (const float*)d_in[14];
  const float* lnfb = (const float*)d_in[15];
  const float* clfw = (const float*)d_in[16];
  const float* clfb = (const float*)d_in[17];
  float* out = (float*)d_out;

  char* ws = (char*)d_ws;
  size_t off = 0;
  auto alloc = [&](size_t bytes) {
    size_t r = off;
    off = (off + bytes + 255) & ~(size_t)255;
    return r;
  };

  const size_t W_QKVG = 12ull * 4608 * 768 * 2;
  const size_t W_O    = 12ull * 768 * 1536 * 2;
  const size_t W_F1GT = 12ull * 6144 * 768 * 2;
  const size_t W_F2   = 12ull * 768 * 3072 * 2;
  const bool big = ws_size >= 720ull * 1024 * 1024;
  const size_t d12 = big ? 1 : 12;

  _Float16* wQKVGh = (_Float16*)(ws + alloc(W_QKVG / d12));
  _Float16* wQKVGl = (_Float16*)(ws + alloc(W_QKVG / d12));
  _Float16* wOh    = (_Float16*)(ws + alloc(W_O    / d12));
  _Float16* wOl    = (_Float16*)(ws + alloc(W_O    / d12));
  _Float16* wF1GTh = (_Float16*)(ws + alloc(W_F1GT / d12));
  _Float16* wF1GTl = (_Float16*)(ws + alloc(W_F1GT / d12));
  _Float16* wF2h   = (_Float16*)(ws + alloc(W_F2   / d12));
  _Float16* wF2l   = (_Float16*)(ws + alloc(W_F2   / d12));

  float*    x    = (float*)(ws + alloc((size_t)BS * DMOD * 4));
  _Float16* hbfH = (_Float16*)(ws + alloc((size_t)BS * DMOD * 2));
  float*    cbuf = (float*)(ws + alloc((size_t)BS * DMOD * 4));   // final-LN scratch
  char*     regB = ws + alloc(8ull * 6291456);                    // 50.3 MB
  float*    accb = (float*)(ws + alloc((size_t)BS * DVAL * 4 + 48ull * SEQ * 4));
  float*    dsacc = accb + (size_t)BS * DVAL;
  float*    ctab = (float*)(ws + alloc(1024 * 32 * 4));
  float*    stab = (float*)(ws + alloc(1024 * 32 * 4));
  float*    pooled = (float*)(ws + alloc(4 * DMOD * 4));

  _Float16* qrbH = (_Float16*)regB;
  _Float16* qrbL = (_Float16*)(regB + 6291456);
  _Float16* krbH = (_Float16*)(regB + 12582912);
  _Float16* krbL = (_Float16*)(regB + 18874368);
  _Float16* vtb  = (_Float16*)(regB + 25165824);
  _Float16* gbuf = (_Float16*)(regB + 37748736);    // 12.58 MB, after vtb
  _Float16* ogbH = (_Float16*)regB;                 // alias (post-attn_part)
  _Float16* ffnbH = (_Float16*)regB;                // alias (post-wo)

  dim3 tb(32, 8);
  const long lsDD = 768l * 768, lsDV = 768l * 1536, lsDF = 768l * 3072;
  const long oQKVG = 4608l * 768, oO = 768l * 1536, oF1 = 6144l * 768, oF2 = 768l * 3072;

  trig_kernel<<<1024, 32, 0, stream>>>(ctab, stab);

  if (big) {
    wcvt_kernel<<<dim3(24, 24, 12), tb, 0, stream>>>(wq,   wQKVGh, wQKVGl, 768, 768,  lsDD, oQKVG, 0,    0);
    wcvt_kernel<<<dim3(24, 24, 12), tb, 0, stream>>>(wk,   wQKVGh, wQKVGl, 768, 768,  lsDD, oQKVG, 768,  0);
    wcvt_kernel<<<dim3(48, 24, 12), tb, 0, stream>>>(wv,   wQKVGh, wQKVGl, 768, 1536, lsDV, oQKVG, 1536, 0);
    wcvt_kernel<<<dim3(48, 24, 12), tb, 0, stream>>>(wg,   wQKVGh, wQKVGl, 768, 1536, lsDV, oQKVG, 3072, 0);
    wcvt_kernel<<<dim3(24, 48, 12), tb, 0, stream>>>(wo,   wOh,    wOl,    1536, 768, lsDV, oO,    0,    0);
    wcvt_kernel<<<dim3(96, 24, 12), tb, 0, stream>>>(fc1,  wF1GTh, wF1GTl, 768, 3072, lsDF, oF1,   0,    1);
    wcvt_kernel<<<dim3(96, 24, 12), tb, 0, stream>>>(gate, wF1GTh, wF1GTl, 768, 3072, lsDF, oF1,   0,    2);
    wcvt_kernel<<<dim3(24, 96, 12), tb, 0, stream>>>(fc2,  wF2h,   wF2l,   3072, 768, lsDF, oF2,   0,    0);
  }

  embed_kernel<<<BS, 192, 0, stream>>>(ids, emb, x);

  for (int l = 0; l < 12; ++l) {
    const _Float16 *Wqkh, *Wqkl, *Woh_, *Wol_, *Wfh, *Wfl, *W2h, *W2l;
    if (big) {
      Wqkh = wQKVGh + (size_t)l * oQKVG;  Wqkl = wQKVGl + (size_t)l * oQKVG;
      Woh_ = wOh    + (size_t)l * oO;     Wol_ = wOl    + (size_t)l * oO;
      Wfh  = wF1GTh + (size_t)l * oF1;    Wfl  = wF1GTl + (size_t)l * oF1;
      W2h  = wF2h   + (size_t)l * oF2;    W2l  = wF2l   + (size_t)l * oF2;
    } else {
      wcvt_kernel<<<dim3(24, 24, 1), tb, 0, stream>>>(wq   + (size_t)l * lsDD, wQKVGh, wQKVGl, 768, 768,  0, 0, 0,    0);
      wcvt_kernel<<<dim3(24, 24, 1), tb, 0, stream>>>(wk   + (size_t)l * lsDD, wQKVGh, wQKVGl, 768, 768,  0, 0, 768,  0);
      wcvt_kernel<<<dim3(48, 24, 1), tb, 0, stream>>>(wv   + (size_t)l * lsDV, wQKVGh, wQKVGl, 768, 1536, 0, 0, 1536, 0);
      wcvt_kernel<<<dim3(48, 24, 1), tb, 0, stream>>>(wg   + (size_t)l * lsDV, wQKVGh, wQKVGl, 768, 1536, 0, 0, 3072, 0);
      wcvt_kernel<<<dim3(24, 48, 1), tb, 0, stream>>>(wo   + (size_t)l * lsDV, wOh,    wOl,    1536, 768, 0, 0, 0,    0);
      wcvt_kernel<<<dim3(96, 24, 1), tb, 0, stream>>>(fc1  + (size_t)l * lsDF, wF1GTh, wF1GTl, 768, 3072, 0, 0, 0,    1);
      wcvt_kernel<<<dim3(96, 24, 1), tb, 0, stream>>>(gate + (size_t)l * lsDF, wF1GTh, wF1GTl, 768, 3072, 0, 0, 0,    2);
      wcvt_kernel<<<dim3(24, 96, 1), tb, 0, stream>>>(fc2  + (size_t)l * lsDF, wF2h,   wF2l,   3072, 768, 0, 0, 0,    0);
      Wqkh = wQKVGh; Wqkl = wQKVGl; Woh_ = wOh; Wol_ = wOl;
      Wfh = wF1GTh; Wfl = wF1GTl; W2h = wF2h; W2l = wF2l;
    }

    ln_h_kernel<<<BS, 256, 0, stream>>>(x, ln1g + l * 768, ln1b + l * 768, hbfH);
    // fused qkvg: 256x128 tile, 8 waves
    gemm_bt<256, 3, 512><<<36 * 16, 512, 0, stream>>>(hbfH, Wqkh, Wqkl, nullptr, nullptr,
                                                      nullptr, qrbH, qrbL, krbH, krbL,
                                                      vtb, gbuf, ctab, stab,
                                                      36, 16, 768, 768, 0);
    hipMemsetAsync(accb, 0, (size_t)BS * DVAL * 4 + 48ull * SEQ * 4, stream);
    attn_part<<<dim3(20, 48), 256, 0, stream>>>(qrbH, qrbL, krbH, krbL, vtb, accb, dsacc);
    attn_norm<<<dim3(32, 48), 256, 0, stream>>>(accb, dsacc, gbuf, ogbH);
    // wo: split-K x2, partials atomically accumulate into x (holds residual)
    gemm_bt<64, 2, 256><<<6 * 64 * 2, 256, 0, stream>>>(ogbH, Woh_, Wol_, x, nullptr,
                                                        nullptr, nullptr, nullptr, nullptr,
                                                        nullptr, nullptr, nullptr, nullptr,
                                                        nullptr, 6, 64, 1536, 768, 768);
    ln_h_kernel<<<BS, 256, 0, stream>>>(x, ln2g + l * 768, ln2b + l * 768, hbfH);
    // f1gt: 256x128 tile, 8 waves, fused silu-gate epilogue
    gemm_bt<256, 1, 512><<<48 * 16, 512, 0, stream>>>(hbfH, Wfh, Wfl, nullptr, nullptr,
                                                      ffnbH, nullptr, nullptr, nullptr,
                                                      nullptr, nullptr, nullptr, nullptr,
                                                      nullptr, 48, 16, 768, 768, 0);
    // f2: split-K x4
    gemm_bt<64, 2, 256><<<6 * 64 * 4, 256, 0, stream>>>(ffnbH, W2h, W2l, x, nullptr,
                                                        nullptr, nullptr, nullptr, nullptr,
                                                        nullptr, nullptr, nullptr, nullptr,
                                                        nullptr, 6, 64, 3072, 768, 768);
  }

  float* xf = cbuf;
  ln_kernel<<<BS, 256, 0, stream>>>(x, lnfg, lnfb, xf);
  pool_kernel<<<dim3(3, 4), 256, 0, stream>>>(xf, pooled);
  clf_kernel<<<4, 128, 0, stream>>>(pooled, clfw, clfb, out);
}

// Round 20
// 6025.309 us; speedup vs baseline: 1.1627x; 1.0297x over previous
//
#include <hip/hip_runtime.h>
#include <cstdint>
#include <cstddef>

// ---------- types ----------
typedef float     f32x4 __attribute__((ext_vector_type(4)));
typedef _Float16  f16x8 __attribute__((ext_vector_type(8)));
typedef _Float16  f16x4 __attribute__((ext_vector_type(4)));
typedef _Float16  f16x2 __attribute__((ext_vector_type(2)));

#define GLD16(g, l)                                                            \
  __builtin_amdgcn_global_load_lds(                                           \
      (const __attribute__((address_space(1))) void*)(g),                     \
      (__attribute__((address_space(3))) void*)(l), 16, 0, 0)

// ---------- constants ----------
#define BQ    4
#define SEQ   1024
#define DMOD  768
#define NH    12
#define DKH   64
#define DVH   128
#define DVAL  1536
#define DFFN  3072
#define BS    4096   /* BQ*SEQ */

// =====================================================================
// theta-shift trig table: ct/st[s][jp], jp=0..31
// =====================================================================
__global__ void trig_kernel(float* __restrict__ ct, float* __restrict__ st)
{
  int s = blockIdx.x, jp = threadIdx.x;   // 1024 x 32
  float ang = exp2f(-(float)jp * (13.287712379549449f / 31.f));
  float a = (float)s * ang;
  ct[s * 32 + jp] = cosf(a);
  st[s * 32 + jp] = sinf(a);
}

// =====================================================================
// weight transpose + f32->f16 hi/lo split into fused layout.
// mode 0: orow = row_off + n  (linear)
// mode 1: fc1 interleave : orow = (n>>6)*128 + ((n>>5)&1)*64 + (n&31)
// mode 2: gate interleave: orow = (n>>6)*128 + ((n>>5)&1)*64 + 32 + (n&31)
// =====================================================================
__global__ void wcvt_kernel(const float* __restrict__ win, _Float16* __restrict__ whi,
                            _Float16* __restrict__ wlo, int K, int N,
                            long in_ls, long out_ls, int row_off, int mode)
{
  __shared__ float tle[32][33];
  size_t ib = (size_t)blockIdx.z * in_ls;
  size_t ob = (size_t)blockIdx.z * out_ls;
  int k0 = blockIdx.y * 32, n0 = blockIdx.x * 32;
  int tx = threadIdx.x, ty = threadIdx.y;
#pragma unroll
  for (int i = 0; i < 4; ++i)
    tle[ty + 8*i][tx] = win[ib + (size_t)(k0 + ty + 8*i) * N + n0 + tx];
  __syncthreads();
#pragma unroll
  for (int i = 0; i < 4; ++i) {
    float v = tle[tx][ty + 8*i];
    _Float16 h = (_Float16)v;
    int n = n0 + ty + 8*i;
    int orow;
    if (mode == 0)      orow = row_off + n;
    else if (mode == 1) orow = (n >> 6) * 128 + ((n >> 5) & 1) * 64 + (n & 31);
    else                orow = (n >> 6) * 128 + ((n >> 5) & 1) * 64 + 32 + (n & 31);
    size_t idx = ob + (size_t)orow * K + k0 + tx;
    whi[idx] = h;
    wlo[idx] = (_Float16)((v - (float)h) * 1024.0f);
  }
}

// =====================================================================
// embedding gather
// =====================================================================
__global__ void embed_kernel(const int* __restrict__ ids, const float* __restrict__ emb,
                             float* __restrict__ x)
{
  int tok = blockIdx.x;
  int id  = ids[tok];
  const float4* s = (const float4*)(emb + (size_t)id * DMOD);
  float4*       d = (float4*)(x + (size_t)tok * DMOD);
  d[threadIdx.x] = s[threadIdx.x];   // block = 192 threads
}

// =====================================================================
// layernorm over 768 -> f32 out (final LN)
// =====================================================================
__global__ __launch_bounds__(256) void ln_kernel(const float* __restrict__ x,
                                                 const float* __restrict__ g,
                                                 const float* __restrict__ bta,
                                                 float* __restrict__ out)
{
  int row = blockIdx.x;
  const float* xr = x + (size_t)row * DMOD;
  int t = threadIdx.x;
  float v0 = xr[t], v1 = xr[t + 256], v2 = xr[t + 512];
  float s  = v0 + v1 + v2;
  float sq = v0*v0 + v1*v1 + v2*v2;
#pragma unroll
  for (int m = 1; m < 64; m <<= 1) { s += __shfl_xor(s, m); sq += __shfl_xor(sq, m); }
  __shared__ float red[8];
  int wv = t >> 6, ln_ = t & 63;
  if (ln_ == 0) { red[wv] = s; red[wv + 4] = sq; }
  __syncthreads();
  s  = red[0] + red[1] + red[2] + red[3];
  sq = red[4] + red[5] + red[6] + red[7];
  float mu = s * (1.f / DMOD);
  float rs = rsqrtf(sq * (1.f / DMOD) - mu * mu + 1e-5f);
  out[(size_t)row * DMOD + t      ] = (v0 - mu) * rs * g[t      ] + bta[t      ];
  out[(size_t)row * DMOD + t + 256] = (v1 - mu) * rs * g[t + 256] + bta[t + 256];
  out[(size_t)row * DMOD + t + 512] = (v2 - mu) * rs * g[t + 512] + bta[t + 512];
}

// =====================================================================
// layernorm over 768 -> f16 (GEMM A-operand)
// =====================================================================
__global__ __launch_bounds__(256) void ln_h_kernel(const float* __restrict__ x,
                                                   const float* __restrict__ g,
                                                   const float* __restrict__ bta,
                                                   _Float16* __restrict__ oh)
{
  int row = blockIdx.x;
  const float* xr = x + (size_t)row * DMOD;
  int t = threadIdx.x;
  float v0 = xr[t], v1 = xr[t + 256], v2 = xr[t + 512];
  float s  = v0 + v1 + v2;
  float sq = v0*v0 + v1*v1 + v2*v2;
#pragma unroll
  for (int m = 1; m < 64; m <<= 1) { s += __shfl_xor(s, m); sq += __shfl_xor(sq, m); }
  __shared__ float red[8];
  int wv = t >> 6, ln_ = t & 63;
  if (ln_ == 0) { red[wv] = s; red[wv + 4] = sq; }
  __syncthreads();
  s  = red[0] + red[1] + red[2] + red[3];
  sq = red[4] + red[5] + red[6] + red[7];
  float mu = s * (1.f / DMOD);
  float rs = rsqrtf(sq * (1.f / DMOD) - mu * mu + 1e-5f);
#pragma unroll
  for (int q = 0; q < 3; ++q) {
    int c = t + q * 256;
    float y = (xr[c] - mu) * rs * g[c] + bta[c];
    oh[(size_t)row * DMOD + c] = (_Float16)y;
  }
}

// =====================================================================
// GEMM: A[M][K](f16) @ (Bh + Bl/1024)[NTOT][K](f16)^T, 2-term split.
// BM x 128 tile, BK=32, TPB/64 waves, global_load_lds, XCD swizzle,
// N-fastest traversal, 2-buffer pipeline, conflict-free LDS swizzle.
// MODE 0: C f32 (opt += R).  MODE 1: silu-gate f16.  MODE 2: split-K
// atomic.  MODE 3: fused qkvg epilogue.
// =====================================================================
template<int BM, int MODE, int TPB>
__global__ __launch_bounds__(TPB) void gemm_bt(const _Float16* __restrict__ Ah,
                                               const _Float16* __restrict__ Bh,
                                               const _Float16* __restrict__ Bl,
                                               float* __restrict__ C,
                                               const float* __restrict__ R,
                                               _Float16* __restrict__ OH,
                                               _Float16* __restrict__ qH,
                                               _Float16* __restrict__ qL,
                                               _Float16* __restrict__ kH,
                                               _Float16* __restrict__ kL,
                                               _Float16* __restrict__ vtb,
                                               _Float16* __restrict__ gb,
                                               const float* __restrict__ ct,
                                               const float* __restrict__ st,
                                               int nbx, int nby, int K, int klen,
                                               int ldc)
{
  constexpr int NW  = TPB / 64;
  constexpr int RPW = 2 * BM / NW;
  constexpr int RI  = RPW / 16;
  constexpr int APW = BM * 64 / NW;
  constexpr int AIS = APW / 1024;
  constexpr int BPW = 8192 / NW;
  constexpr int BIS = BPW / 1024;
  __shared__ char sAh[2][BM * 64];
  __shared__ char sBh[2][8192];
  __shared__ char sBl[2][8192];
  const int tid = threadIdx.x, lane = tid & 63, w = tid >> 6;

  int nwg = gridDim.x, bid = blockIdx.x;
  int qq = nwg >> 3, rr = nwg & 7;
  int xc = bid & 7, ix = bid >> 3;
  int wg = (xc < rr ? xc * (qq + 1) : rr * (qq + 1) + (xc - rr) * qq) + ix;
  int bx = wg % nbx;
  int rem = wg / nbx;
  int by = rem % nby;
  int kbase = (rem / nby) * klen;

  const int m0 = by * BM, n0 = bx * 128;
  const int wm = (w >> 1) * RPW, wn = (w & 1) * 64;
  const int lhi = lane >> 4, llo = lane & 15;

  const f32x4 fz = {0.f, 0.f, 0.f, 0.f};
  f32x4 accH[RI][4], accM[RI][4];
#pragma unroll
  for (int i = 0; i < RI; ++i)
#pragma unroll
    for (int j = 0; j < 4; ++j) { accH[i][j] = fz; accM[i][j] = fz; }

  auto stage = [&](int buf, int k0) {
#pragma unroll
    for (int i = 0; i < AIS; ++i) {           // A plane
      int off = w * APW + i * 1024 + lane * 16;
      int r = off >> 6, c = (off >> 4) & 3;
      size_t go = (size_t)r * K + ((c ^ ((r >> 1) & 3)) << 3);
      GLD16(Ah + (size_t)m0 * K + k0 + go, &sAh[buf][w * APW + i * 1024]);
    }
#pragma unroll
    for (int i = 0; i < BIS; ++i) {           // B planes (hi+lo)
      int off = w * BPW + i * 1024 + lane * 16;
      int r = off >> 6, c = (off >> 4) & 3;
      size_t go = (size_t)r * K + ((c ^ ((r >> 1) & 3)) << 3);
      GLD16(Bh + (size_t)n0 * K + k0 + go, &sBh[buf][w * BPW + i * 1024]);
      GLD16(Bl + (size_t)n0 * K + k0 + go, &sBl[buf][w * BPW + i * 1024]);
    }
  };

  stage(0, kbase);
  asm volatile("s_waitcnt vmcnt(0)" ::: "memory");
  __builtin_amdgcn_s_barrier();

  int cur = 0;
  const int kend = kbase + klen;
  for (int k0 = kbase; k0 < kend; k0 += 32) {
    if (k0 + 32 < kend) stage(cur ^ 1, k0 + 32);

    f16x8 ah[RI], bh[4], bl[4];
#pragma unroll
    for (int r = 0; r < RI; ++r) {
      int ra = wm + r * 16 + llo;
      ah[r] = *(const f16x8*)(&sAh[cur][ra * 64 + ((lhi ^ ((ra >> 1) & 3)) << 4)]);
    }
#pragma unroll
    for (int r = 0; r < 4; ++r) {
      int rb = wn + r * 16 + llo;
      int sb = rb * 64 + ((lhi ^ ((rb >> 1) & 3)) << 4);
      bh[r] = *(const f16x8*)(&sBh[cur][sb]);
      bl[r] = *(const f16x8*)(&sBl[cur][sb]);
    }
#pragma unroll
    for (int i = 0; i < RI; ++i)
#pragma unroll
      for (int j = 0; j < 4; ++j) {
        accH[i][j] = __builtin_amdgcn_mfma_f32_16x16x32_f16(ah[i], bh[j], accH[i][j], 0, 0, 0);
        accM[i][j] = __builtin_amdgcn_mfma_f32_16x16x32_f16(ah[i], bl[j], accM[i][j], 0, 0, 0);
      }

    asm volatile("s_waitcnt vmcnt(0)" ::: "memory");
    __builtin_amdgcn_s_barrier();
    cur ^= 1;
  }

  if constexpr (MODE == 0) {
#pragma unroll
    for (int i = 0; i < RI; ++i)
#pragma unroll
      for (int j = 0; j < 4; ++j)
#pragma unroll
        for (int rg = 0; rg < 4; ++rg) {
          int m = m0 + wm + i * 16 + lhi * 4 + rg;
          int n = n0 + wn + j * 16 + llo;
          size_t idx = (size_t)m * ldc + n;
          float v = accH[i][j][rg] + accM[i][j][rg] * (1.0f / 1024.0f);
          if (R) v += R[idx];
          C[idx] = v;
        }
  } else if constexpr (MODE == 2) {
#pragma unroll
    for (int i = 0; i < RI; ++i)
#pragma unroll
      for (int j = 0; j < 4; ++j)
#pragma unroll
        for (int rg = 0; rg < 4; ++rg) {
          int m = m0 + wm + i * 16 + lhi * 4 + rg;
          int n = n0 + wn + j * 16 + llo;
          float v = accH[i][j][rg] + accM[i][j][rg] * (1.0f / 1024.0f);
          atomicAdd(&C[(size_t)m * ldc + n], v);
        }
  } else if constexpr (MODE == 1) {
#pragma unroll
    for (int i = 0; i < RI; ++i)
#pragma unroll
      for (int j = 0; j < 2; ++j)
#pragma unroll
        for (int rg = 0; rg < 4; ++rg) {
          int m = m0 + wm + i * 16 + lhi * 4 + rg;
          int n = (n0 >> 1) + (wn >> 1) + j * 16 + llo;
          float f1 = accH[i][j][rg]     + accM[i][j][rg]     * (1.0f / 1024.0f);
          float gv = accH[i][j + 2][rg] + accM[i][j + 2][rg] * (1.0f / 1024.0f);
          float y = f1 / (1.f + expf(-f1)) * gv;
          OH[(size_t)m * 3072 + n] = (_Float16)y;
        }
  } else {
    // MODE 3: fused qkvg epilogue (block-uniform region select on n0)
    if (n0 < 1536) {
      bool isq = n0 < 768;
      _Float16* dH = isq ? qH : kH;
      _Float16* dL = isq ? qL : kL;
      int nbase = isq ? n0 : n0 - 768;
#pragma unroll
      for (int i = 0; i < RI; ++i)
#pragma unroll
        for (int j = 0; j < 4; ++j) {
          int n = nbase + wn + j * 16 + llo;
          int h = n >> 6, idk = n & 63, jp = idk >> 1;
          float sgn = (n & 1) ? 1.f : -1.f;
#pragma unroll
          for (int rg = 0; rg < 4; ++rg) {
            int m = m0 + wm + i * 16 + lhi * 4 + rg;
            int s = m & (SEQ - 1), b = m >> 10;
            float v = accH[i][j][rg] + accM[i][j][rg] * (1.0f / 1024.0f);
            float p = __shfl_xor(v, 1);
            float cc = ct[s * 32 + jp], sn = st[s * 32 + jp];
            float r = v * cc + sgn * p * sn;
            _Float16 hh = (_Float16)r;
            size_t dst = ((size_t)(b * NH + h) * SEQ + s) * DKH + idk;
            dH[dst] = hh;
            dL[dst] = (_Float16)((r - (float)hh) * 1024.f);
          }
        }
    } else if (n0 < 3072) {
      int nbase = n0 - 1536;
#pragma unroll
      for (int i = 0; i < RI; ++i) {
        int m = m0 + wm + i * 16 + lhi * 4;
        int s = m & (SEQ - 1), b = m >> 10;
#pragma unroll
        for (int j = 0; j < 4; ++j) {
          int n = nbase + wn + j * 16 + llo;
          int h = n >> 7, d = n & 127;
          f16x4 tv;
#pragma unroll
          for (int rg = 0; rg < 4; ++rg)
            tv[rg] = (_Float16)(accH[i][j][rg] + accM[i][j][rg] * (1.0f / 1024.0f));
          *(f16x4*)(vtb + ((size_t)(b * NH + h) * DVH + d) * SEQ + s) = tv;
        }
      }
    } else {
      int nbase = n0 - 3072;
#pragma unroll
      for (int i = 0; i < RI; ++i)
#pragma unroll
        for (int j = 0; j < 4; ++j) {
          int n = nbase + wn + j * 16 + llo;
#pragma unroll
          for (int rg = 0; rg < 4; ++rg) {
            int m = m0 + wm + i * 16 + lhi * 4 + rg;
            float v = accH[i][j][rg] + accM[i][j][rg] * (1.0f / 1024.0f);
            gb[(size_t)m * DVAL + n] = (_Float16)v;
          }
        }
    }
  }
}

// =====================================================================
// retention stage 1 (split-K chunk=1): per (bh, rb, ct): one QK^T(3-term)
// -> decay -> PV partial; atomicAdd into accbuf and dsacc.
// 36x48 = 1728 uniform blocks — max parallelism (measured scaling law:
// parallelism beats write thrift for this kernel).
// =====================================================================
__global__ __launch_bounds__(256) void attn_part(const _Float16* __restrict__ qrH_,
                                                 const _Float16* __restrict__ qrL_,
                                                 const _Float16* __restrict__ krH_,
                                                 const _Float16* __restrict__ krL_,
                                                 const _Float16* __restrict__ vt,
                                                 float* __restrict__ accb,
                                                 float* __restrict__ dsacc)
{
  static const int RBt[36] = {0,1,1,2,2,2,3,3,3,3,4,4,4,4,4,5,5,5,5,5,5,
                              6,6,6,6,6,6,6,7,7,7,7,7,7,7,7};
  static const int CTt[36] = {0,0,1,0,1,2,0,1,2,3,0,1,2,3,4,0,1,2,3,4,5,
                              0,1,2,3,4,5,6,0,1,2,3,4,5,6,7};
  __shared__ char pbuf[32768];          // 4 waves x [32][128] f16, XOR-swizzled
  const int tid = threadIdx.x, lane = tid & 63, w = tid >> 6;
  const int rb = RBt[blockIdx.x], ctc = CTt[blockIdx.x];
  const int bh = blockIdx.y;            // 0..47
  const int h = bh % NH;
  const int wrow0 = rb * 128 + w * 32;
  const int lhi = lane >> 4, llo = lane & 15;

  const _Float16* qbhH = qrH_ + (size_t)bh * SEQ * DKH;
  const _Float16* qbhL = qrL_ + (size_t)bh * SEQ * DKH;
  const _Float16* kbhH = krH_ + (size_t)bh * SEQ * DKH;
  const _Float16* kbhL = krL_ + (size_t)bh * SEQ * DKH;
  const _Float16* vbh  = vt   + (size_t)bh * DVH * SEQ;

  const float lg = log1pf(-exp2f(-(float)(5 + h)));   // ln(gamma_h)
  const float den_lg = expm1f(lg);                    // gamma - 1

  float invn[2][4];
#pragma unroll
  for (int rf = 0; rf < 2; ++rf)
#pragma unroll
    for (int rg = 0; rg < 4; ++rg) {
      int n = wrow0 + rf * 16 + lhi * 4 + rg;
      float sumD = expm1f((float)(n + 1) * lg) / den_lg;  // (1-g^{n+1})/(1-g)
      invn[rf][rg] = rsqrtf(sumD) * 0.125f;               // fold DK^-0.5
    }

  float gm[8];
#pragma unroll
  for (int fc = 0; fc < 8; ++fc)
    gm[fc] = expf(-(float)(fc * 16 + llo) * lg);

  f16x8 qaH[2][2], qaL[2][2];
#pragma unroll
  for (int rf = 0; rf < 2; ++rf)
#pragma unroll
    for (int kt = 0; kt < 2; ++kt) {
      size_t qo = (size_t)(wrow0 + rf * 16 + llo) * DKH + kt * 32 + lhi * 8;
      qaH[rf][kt] = *(const f16x8*)(qbhH + qo);
      qaL[rf][kt] = *(const f16x8*)(qbhL + qo);
    }

  const f32x4 fz = {0.f, 0.f, 0.f, 0.f};
  f32x4 acc[2][8];
#pragma unroll
  for (int i = 0; i < 2; ++i)
#pragma unroll
    for (int j = 0; j < 8; ++j) acc[i][j] = fz;
  float dsum[2][4] = {{0, 0, 0, 0}, {0, 0, 0, 0}};

  {
    const bool diag = (ctc == rb);
    float fn[2][4];
#pragma unroll
    for (int rf = 0; rf < 2; ++rf)
#pragma unroll
      for (int rg = 0; rg < 4; ++rg) {
        int n = wrow0 + rf * 16 + lhi * 4 + rg;
        fn[rf][rg] = expf((float)(n - ctc * 128) * lg) * invn[rf][rg];
      }

#pragma unroll
    for (int fc = 0; fc < 8; ++fc) {
      f32x4 pH[2] = {fz, fz}, pM[2] = {fz, fz};
#pragma unroll
      for (int kt = 0; kt < 2; ++kt) {
        size_t kro = (size_t)(ctc * 128 + fc * 16 + llo) * DKH + kt * 32 + lhi * 8;
        f16x8 kbH = *(const f16x8*)(kbhH + kro);
        f16x8 kbL = *(const f16x8*)(kbhL + kro);
        pH[0] = __builtin_amdgcn_mfma_f32_16x16x32_f16(qaH[0][kt], kbH, pH[0], 0, 0, 0);
        pH[1] = __builtin_amdgcn_mfma_f32_16x16x32_f16(qaH[1][kt], kbH, pH[1], 0, 0, 0);
        pM[0] = __builtin_amdgcn_mfma_f32_16x16x32_f16(qaL[0][kt], kbH, pM[0], 0, 0, 0);
        pM[1] = __builtin_amdgcn_mfma_f32_16x16x32_f16(qaL[1][kt], kbH, pM[1], 0, 0, 0);
        pM[0] = __builtin_amdgcn_mfma_f32_16x16x32_f16(qaH[0][kt], kbL, pM[0], 0, 0, 0);
        pM[1] = __builtin_amdgcn_mfma_f32_16x16x32_f16(qaH[1][kt], kbL, pM[1], 0, 0, 0);
      }
#pragma unroll
      for (int rf = 0; rf < 2; ++rf)
#pragma unroll
        for (int rg = 0; rg < 4; ++rg) {
          float pv = (pH[rf][rg] + pM[rf][rg] * (1.f / 1024.f)) * fn[rf][rg] * gm[fc];
          if (diag) {
            int e = (wrow0 + rf * 16 + lhi * 4 + rg) - (ctc * 128 + fc * 16 + llo);
            if (e < 0) pv = 0.f;
          }
          dsum[rf][rg] += fabsf(pv);
          int prow = rf * 16 + lhi * 4 + rg;
          int byte = (w << 13) + prow * 256 + (fc * 16 + llo) * 2;
          byte ^= (prow & 7) << 4;
          *(_Float16*)(pbuf + byte) = (_Float16)pv;
        }
    }
    // each wave reads only its own pbuf slice — no barrier needed

    f16x8 pa[2][4];
#pragma unroll
    for (int rf2 = 0; rf2 < 2; ++rf2)
#pragma unroll
      for (int kt = 0; kt < 4; ++kt) {
        int prow = rf2 * 16 + llo;
        int byte = (w << 13) + prow * 256 + kt * 64 + lhi * 16;
        byte ^= (prow & 7) << 4;
        pa[rf2][kt] = *(const f16x8*)(pbuf + byte);
      }
#pragma unroll
    for (int fd = 0; fd < 8; ++fd)
#pragma unroll
      for (int kt = 0; kt < 4; ++kt) {
        f16x8 vb = *(const f16x8*)(vbh + (size_t)(fd * 16 + llo) * SEQ + ctc * 128 + kt * 32 + lhi * 8);
        acc[0][fd] = __builtin_amdgcn_mfma_f32_16x16x32_f16(pa[0][kt], vb, acc[0][fd], 0, 0, 0);
        acc[1][fd] = __builtin_amdgcn_mfma_f32_16x16x32_f16(pa[1][kt], vb, acc[1][fd], 0, 0, 0);
      }
  }

  float* ab = accb + (size_t)bh * SEQ * DVH;
#pragma unroll
  for (int rf = 0; rf < 2; ++rf)
#pragma unroll
    for (int rg = 0; rg < 4; ++rg) {
      float d = dsum[rf][rg];
      d += __shfl_xor(d, 1); d += __shfl_xor(d, 2);
      d += __shfl_xor(d, 4); d += __shfl_xor(d, 8);
      int row = wrow0 + rf * 16 + lhi * 4 + rg;
      if (llo == 0) atomicAdd(&dsacc[bh * SEQ + row], d);
#pragma unroll
      for (int fd = 0; fd < 8; ++fd)
        atomicAdd(&ab[(size_t)row * DVH + fd * 16 + llo], acc[rf][fd][rg]);
    }
}

// =====================================================================
// retention stage 2: row-normalize + group-norm + silu(g)*o fused,
// g read as f16 dense [row][1536]; writes ogb f16 [B*S][1536]
// =====================================================================
__global__ __launch_bounds__(256) void attn_norm(const float* __restrict__ accb,
                                                 const float* __restrict__ dsacc,
                                                 const _Float16* __restrict__ gsrc,
                                                 _Float16* __restrict__ oh)
{
  int bh = blockIdx.y, h = bh % NH, b = bh / NH;
  int s0 = blockIdx.x * 32;
  int lane = threadIdx.x & 63, w = threadIdx.x >> 6;
  const float* ab = accb + ((size_t)bh * SEQ + s0) * DVH;
#pragma unroll
  for (int i = 0; i < 8; ++i) {
    int r = w * 8 + i;
    size_t row = (size_t)(b * SEQ + s0 + r);
    float2 v = *(const float2*)(ab + (size_t)r * DVH + lane * 2);
    float inv = 1.f / fmaxf(dsacc[bh * SEQ + s0 + r], 1.f);
    v.x *= inv; v.y *= inv;
    float ss = v.x * v.x + v.y * v.y;
#pragma unroll
    for (int m = 1; m < 64; m <<= 1) ss += __shfl_xor(ss, m);
    float rs = rsqrtf(ss * (1.f / 128.f) + 1e-5f);
    float o0 = v.x * rs, o1 = v.y * rs;
    f16x2 gg = *(const f16x2*)(gsrc + row * DVAL + h * DVH + lane * 2);
    float gx = (float)gg[0], gy = (float)gg[1];
    float y0 = gx / (1.f + expf(-gx)) * o0;
    float y1 = gy / (1.f + expf(-gy)) * o1;
    f16x2 vh = {(_Float16)y0, (_Float16)y1};
    *(f16x2*)(oh + row * DVAL + h * DVH + lane * 2) = vh;
  }
}

// =====================================================================
// mean pool over S
// =====================================================================
__global__ void pool_kernel(const float* __restrict__ xf, float* __restrict__ pooled)
{
  int d = blockIdx.x * 256 + threadIdx.x;   // grid.x = 3
  int b = blockIdx.y;
  float acc = 0.f;
  for (int s = 0; s < SEQ; ++s) acc += xf[((size_t)(b * SEQ + s)) * DMOD + d];
  pooled[b * DMOD + d] = acc * (1.f / SEQ);
}

// =====================================================================
// classifier
// =====================================================================
__global__ void clf_kernel(const float* __restrict__ pooled, const float* __restrict__ cw,
                           const float* __restrict__ cb, float* __restrict__ out)
{
  int b = blockIdx.x, c = threadIdx.x;
  if (c < 100) {
    float acc = cb[c];
    for (int d = 0; d < DMOD; ++d) acc += pooled[b * DMOD + d] * cw[d * 100 + c];
    out[b * 100 + c] = acc;
  }
}

// =====================================================================
// host
// =====================================================================
extern "C" void kernel_launch(void* const* d_in, const int* in_sizes, int n_in,
                              void* d_out, int out_size, void* d_ws, size_t ws_size,
                              hipStream_t stream)
{
  const int*   ids  = (const int*)d_in[0];
  const float* emb  = (const float*)d_in[1];
  const float* wq   = (const float*)d_in[2];
  const float* wk   = (const float*)d_in[3];
  const float* wv   = (const float*)d_in[4];
  const float* wg   = (const float*)d_in[5];
  const float* wo   = (const float*)d_in[6];
  const float* ln1g = (const float*)d_in[7];
  const float* ln1b = (const float*)d_in[8];
  const float* ln2g = (const float*)d_in[9];
  const float* ln2b = (const float*)d_in[10];
  const float* fc1  = (const float*)d_in[11];
  const float* gate = (const float*)d_in[12];
  const float* fc2  = (const float*)d_in[13];
  const float* lnfg = (const float*)d_in[14];
  const float* lnfb = (const float*)d_in[15];
  const float* clfw = (const float*)d_in[16];
  const float* clfb = (const float*)d_in[17];
  float* out = (float*)d_out;

  char* ws = (char*)d_ws;
  size_t off = 0;
  auto alloc = [&](size_t bytes) {
    size_t r = off;
    off = (off + bytes + 255) & ~(size_t)255;
    return r;
  };

  const size_t W_QKVG = 12ull * 4608 * 768 * 2;
  const size_t W_O    = 12ull * 768 * 1536 * 2;
  const size_t W_F1GT = 12ull * 6144 * 768 * 2;
  const size_t W_F2   = 12ull * 768 * 3072 * 2;
  const bool big = ws_size >= 720ull * 1024 * 1024;
  const size_t d12 = big ? 1 : 12;

  _Float16* wQKVGh = (_Float16*)(ws + alloc(W_QKVG / d12));
  _Float16* wQKVGl = (_Float16*)(ws + alloc(W_QKVG / d12));
  _Float16* wOh    = (_Float16*)(ws + alloc(W_O    / d12));
  _Float16* wOl    = (_Float16*)(ws + alloc(W_O    / d12));
  _Float16* wF1GTh = (_Float16*)(ws + alloc(W_F1GT / d12));
  _Float16* wF1GTl = (_Float16*)(ws + alloc(W_F1GT / d12));
  _Float16* wF2h   = (_Float16*)(ws + alloc(W_F2   / d12));
  _Float16* wF2l   = (_Float16*)(ws + alloc(W_F2   / d12));

  float*    x    = (float*)(ws + alloc((size_t)BS * DMOD * 4));
  _Float16* hbfH = (_Float16*)(ws + alloc((size_t)BS * DMOD * 2));
  float*    cbuf = (float*)(ws + alloc((size_t)BS * DMOD * 4));   // final-LN scratch
  char*     regB = ws + alloc(8ull * 6291456);                    // 50.3 MB
  float*    accb = (float*)(ws + alloc((size_t)BS * DVAL * 4 + 48ull * SEQ * 4));
  float*    dsacc = accb + (size_t)BS * DVAL;
  float*    ctab = (float*)(ws + alloc(1024 * 32 * 4));
  float*    stab = (float*)(ws + alloc(1024 * 32 * 4));
  float*    pooled = (float*)(ws + alloc(4 * DMOD * 4));

  _Float16* qrbH = (_Float16*)regB;
  _Float16* qrbL = (_Float16*)(regB + 6291456);
  _Float16* krbH = (_Float16*)(regB + 12582912);
  _Float16* krbL = (_Float16*)(regB + 18874368);
  _Float16* vtb  = (_Float16*)(regB + 25165824);
  _Float16* gbuf = (_Float16*)(regB + 37748736);    // 12.58 MB, after vtb
  _Float16* ogbH = (_Float16*)regB;                 // alias (post-attn_part)
  _Float16* ffnbH = (_Float16*)regB;                // alias (post-wo)

  dim3 tb(32, 8);
  const long lsDD = 768l * 768, lsDV = 768l * 1536, lsDF = 768l * 3072;
  const long oQKVG = 4608l * 768, oO = 768l * 1536, oF1 = 6144l * 768, oF2 = 768l * 3072;

  trig_kernel<<<1024, 32, 0, stream>>>(ctab, stab);

  if (big) {
    wcvt_kernel<<<dim3(24, 24, 12), tb, 0, stream>>>(wq,   wQKVGh, wQKVGl, 768, 768,  lsDD, oQKVG, 0,    0);
    wcvt_kernel<<<dim3(24, 24, 12), tb, 0, stream>>>(wk,   wQKVGh, wQKVGl, 768, 768,  lsDD, oQKVG, 768,  0);
    wcvt_kernel<<<dim3(48, 24, 12), tb, 0, stream>>>(wv,   wQKVGh, wQKVGl, 768, 1536, lsDV, oQKVG, 1536, 0);
    wcvt_kernel<<<dim3(48, 24, 12), tb, 0, stream>>>(wg,   wQKVGh, wQKVGl, 768, 1536, lsDV, oQKVG, 3072, 0);
    wcvt_kernel<<<dim3(24, 48, 12), tb, 0, stream>>>(wo,   wOh,    wOl,    1536, 768, lsDV, oO,    0,    0);
    wcvt_kernel<<<dim3(96, 24, 12), tb, 0, stream>>>(fc1,  wF1GTh, wF1GTl, 768, 3072, lsDF, oF1,   0,    1);
    wcvt_kernel<<<dim3(96, 24, 12), tb, 0, stream>>>(gate, wF1GTh, wF1GTl, 768, 3072, lsDF, oF1,   0,    2);
    wcvt_kernel<<<dim3(24, 96, 12), tb, 0, stream>>>(fc2,  wF2h,   wF2l,   3072, 768, lsDF, oF2,   0,    0);
  }

  embed_kernel<<<BS, 192, 0, stream>>>(ids, emb, x);

  for (int l = 0; l < 12; ++l) {
    const _Float16 *Wqkh, *Wqkl, *Woh_, *Wol_, *Wfh, *Wfl, *W2h, *W2l;
    if (big) {
      Wqkh = wQKVGh + (size_t)l * oQKVG;  Wqkl = wQKVGl + (size_t)l * oQKVG;
      Woh_ = wOh    + (size_t)l * oO;     Wol_ = wOl    + (size_t)l * oO;
      Wfh  = wF1GTh + (size_t)l * oF1;    Wfl  = wF1GTl + (size_t)l * oF1;
      W2h  = wF2h   + (size_t)l * oF2;    W2l  = wF2l   + (size_t)l * oF2;
    } else {
      wcvt_kernel<<<dim3(24, 24, 1), tb, 0, stream>>>(wq   + (size_t)l * lsDD, wQKVGh, wQKVGl, 768, 768,  0, 0, 0,    0);
      wcvt_kernel<<<dim3(24, 24, 1), tb, 0, stream>>>(wk   + (size_t)l * lsDD, wQKVGh, wQKVGl, 768, 768,  0, 0, 768,  0);
      wcvt_kernel<<<dim3(48, 24, 1), tb, 0, stream>>>(wv   + (size_t)l * lsDV, wQKVGh, wQKVGl, 768, 1536, 0, 0, 1536, 0);
      wcvt_kernel<<<dim3(48, 24, 1), tb, 0, stream>>>(wg   + (size_t)l * lsDV, wQKVGh, wQKVGl, 768, 1536, 0, 0, 3072, 0);
      wcvt_kernel<<<dim3(24, 48, 1), tb, 0, stream>>>(wo   + (size_t)l * lsDV, wOh,    wOl,    1536, 768, 0, 0, 0,    0);
      wcvt_kernel<<<dim3(96, 24, 1), tb, 0, stream>>>(fc1  + (size_t)l * lsDF, wF1GTh, wF1GTl, 768, 3072, 0, 0, 0,    1);
      wcvt_kernel<<<dim3(96, 24, 1), tb, 0, stream>>>(gate + (size_t)l * lsDF, wF1GTh, wF1GTl, 768, 3072, 0, 0, 0,    2);
      wcvt_kernel<<<dim3(24, 96, 1), tb, 0, stream>>>(fc2  + (size_t)l * lsDF, wF2h,   wF2l,   3072, 768, 0, 0, 0,    0);
      Wqkh = wQKVGh; Wqkl = wQKVGl; Woh_ = wOh; Wol_ = wOl;
      Wfh = wF1GTh; Wfl = wF1GTl; W2h = wF2h; W2l = wF2l;
    }

    ln_h_kernel<<<BS, 256, 0, stream>>>(x, ln1g + l * 768, ln1b + l * 768, hbfH);
    // fused qkvg: 256x128 tile, 8 waves
    gemm_bt<256, 3, 512><<<36 * 16, 512, 0, stream>>>(hbfH, Wqkh, Wqkl, nullptr, nullptr,
                                                      nullptr, qrbH, qrbL, krbH, krbL,
                                                      vtb, gbuf, ctab, stab,
                                                      36, 16, 768, 768, 0);
    hipMemsetAsync(accb, 0, (size_t)BS * DVAL * 4 + 48ull * SEQ * 4, stream);
    attn_part<<<dim3(36, 48), 256, 0, stream>>>(qrbH, qrbL, krbH, krbL, vtb, accb, dsacc);
    attn_norm<<<dim3(32, 48), 256, 0, stream>>>(accb, dsacc, gbuf, ogbH);
    // wo: split-K x2, partials atomically accumulate into x (holds residual)
    gemm_bt<64, 2, 256><<<6 * 64 * 2, 256, 0, stream>>>(ogbH, Woh_, Wol_, x, nullptr,
                                                        nullptr, nullptr, nullptr, nullptr,
                                                        nullptr, nullptr, nullptr, nullptr,
                                                        nullptr, 6, 64, 1536, 768, 768);
    ln_h_kernel<<<BS, 256, 0, stream>>>(x, ln2g + l * 768, ln2b + l * 768, hbfH);
    // f1gt: 256x128 tile, 8 waves, fused silu-gate epilogue
    gemm_bt<256, 1, 512><<<48 * 16, 512, 0, stream>>>(hbfH, Wfh, Wfl, nullptr, nullptr,
                                                      ffnbH, nullptr, nullptr, nullptr,
                                                      nullptr, nullptr, nullptr, nullptr,
                                                      nullptr, 48, 16, 768, 768, 0);
    // f2: split-K x4
    gemm_bt<64, 2, 256><<<6 * 64 * 4, 256, 0, stream>>>(ffnbH, W2h, W2l, x, nullptr,
                                                        nullptr, nullptr, nullptr, nullptr,
                                                        nullptr, nullptr, nullptr, nullptr,
                                                        nullptr, 6, 64, 3072, 768, 768);
  }

  float* xf = cbuf;
  ln_kernel<<<BS, 256, 0, stream>>>(x, lnfg, lnfb, xf);
  pool_kernel<<<dim3(3, 4), 256, 0, stream>>>(xf, pooled);
  clf_kernel<<<4, 128, 0, stream>>>(pooled, clfw, clfb, out);
}

// Round 21
// 6010.477 us; speedup vs baseline: 1.1655x; 1.0025x over previous
//
#include <hip/hip_runtime.h>
#include <cstdint>
#include <cstddef>

// ---------- types ----------
typedef float     f32x4 __attribute__((ext_vector_type(4)));
typedef _Float16  f16x8 __attribute__((ext_vector_type(8)));
typedef _Float16  f16x4 __attribute__((ext_vector_type(4)));
typedef _Float16  f16x2 __attribute__((ext_vector_type(2)));

#define GLD16(g, l)                                                            \
  __builtin_amdgcn_global_load_lds(                                           \
      (const __attribute__((address_space(1))) void*)(g),                     \
      (__attribute__((address_space(3))) void*)(l), 16, 0, 0)

// ---------- constants ----------
#define BQ    4
#define SEQ   1024
#define DMOD  768
#define NH    12
#define DKH   64
#define DVH   128
#define DVAL  1536
#define DFFN  3072
#define BS    4096   /* BQ*SEQ */

// =====================================================================
// theta-shift trig table: ct/st[s][jp], jp=0..31
// =====================================================================
__global__ void trig_kernel(float* __restrict__ ct, float* __restrict__ st)
{
  int s = blockIdx.x, jp = threadIdx.x;   // 1024 x 32
  float ang = exp2f(-(float)jp * (13.287712379549449f / 31.f));
  float a = (float)s * ang;
  ct[s * 32 + jp] = cosf(a);
  st[s * 32 + jp] = sinf(a);
}

// =====================================================================
// weight transpose + f32->f16 hi/lo split into fused layout.
// mode 0: orow = row_off + n  (linear)
// mode 1: fc1 interleave : orow = (n>>6)*128 + ((n>>5)&1)*64 + (n&31)
// mode 2: gate interleave: orow = (n>>6)*128 + ((n>>5)&1)*64 + 32 + (n&31)
// =====================================================================
__global__ void wcvt_kernel(const float* __restrict__ win, _Float16* __restrict__ whi,
                            _Float16* __restrict__ wlo, int K, int N,
                            long in_ls, long out_ls, int row_off, int mode)
{
  __shared__ float tle[32][33];
  size_t ib = (size_t)blockIdx.z * in_ls;
  size_t ob = (size_t)blockIdx.z * out_ls;
  int k0 = blockIdx.y * 32, n0 = blockIdx.x * 32;
  int tx = threadIdx.x, ty = threadIdx.y;
#pragma unroll
  for (int i = 0; i < 4; ++i)
    tle[ty + 8*i][tx] = win[ib + (size_t)(k0 + ty + 8*i) * N + n0 + tx];
  __syncthreads();
#pragma unroll
  for (int i = 0; i < 4; ++i) {
    float v = tle[tx][ty + 8*i];
    _Float16 h = (_Float16)v;
    int n = n0 + ty + 8*i;
    int orow;
    if (mode == 0)      orow = row_off + n;
    else if (mode == 1) orow = (n >> 6) * 128 + ((n >> 5) & 1) * 64 + (n & 31);
    else                orow = (n >> 6) * 128 + ((n >> 5) & 1) * 64 + 32 + (n & 31);
    size_t idx = ob + (size_t)orow * K + k0 + tx;
    whi[idx] = h;
    wlo[idx] = (_Float16)((v - (float)h) * 1024.0f);
  }
}

// =====================================================================
// embedding gather
// =====================================================================
__global__ void embed_kernel(const int* __restrict__ ids, const float* __restrict__ emb,
                             float* __restrict__ x)
{
  int tok = blockIdx.x;
  int id  = ids[tok];
  const float4* s = (const float4*)(emb + (size_t)id * DMOD);
  float4*       d = (float4*)(x + (size_t)tok * DMOD);
  d[threadIdx.x] = s[threadIdx.x];   // block = 192 threads
}

// =====================================================================
// layernorm over 768 -> f32 out (final LN)
// =====================================================================
__global__ __launch_bounds__(256) void ln_kernel(const float* __restrict__ x,
                                                 const float* __restrict__ g,
                                                 const float* __restrict__ bta,
                                                 float* __restrict__ out)
{
  int row = blockIdx.x;
  const float* xr = x + (size_t)row * DMOD;
  int t = threadIdx.x;
  float v0 = xr[t], v1 = xr[t + 256], v2 = xr[t + 512];
  float s  = v0 + v1 + v2;
  float sq = v0*v0 + v1*v1 + v2*v2;
#pragma unroll
  for (int m = 1; m < 64; m <<= 1) { s += __shfl_xor(s, m); sq += __shfl_xor(sq, m); }
  __shared__ float red[8];
  int wv = t >> 6, ln_ = t & 63;
  if (ln_ == 0) { red[wv] = s; red[wv + 4] = sq; }
  __syncthreads();
  s  = red[0] + red[1] + red[2] + red[3];
  sq = red[4] + red[5] + red[6] + red[7];
  float mu = s * (1.f / DMOD);
  float rs = rsqrtf(sq * (1.f / DMOD) - mu * mu + 1e-5f);
  out[(size_t)row * DMOD + t      ] = (v0 - mu) * rs * g[t      ] + bta[t      ];
  out[(size_t)row * DMOD + t + 256] = (v1 - mu) * rs * g[t + 256] + bta[t + 256];
  out[(size_t)row * DMOD + t + 512] = (v2 - mu) * rs * g[t + 512] + bta[t + 512];
}

// =====================================================================
// layernorm over 768 -> f16 (GEMM A-operand)
// =====================================================================
__global__ __launch_bounds__(256) void ln_h_kernel(const float* __restrict__ x,
                                                   const float* __restrict__ g,
                                                   const float* __restrict__ bta,
                                                   _Float16* __restrict__ oh)
{
  int row = blockIdx.x;
  const float* xr = x + (size_t)row * DMOD;
  int t = threadIdx.x;
  float v0 = xr[t], v1 = xr[t + 256], v2 = xr[t + 512];
  float s  = v0 + v1 + v2;
  float sq = v0*v0 + v1*v1 + v2*v2;
#pragma unroll
  for (int m = 1; m < 64; m <<= 1) { s += __shfl_xor(s, m); sq += __shfl_xor(sq, m); }
  __shared__ float red[8];
  int wv = t >> 6, ln_ = t & 63;
  if (ln_ == 0) { red[wv] = s; red[wv + 4] = sq; }
  __syncthreads();
  s  = red[0] + red[1] + red[2] + red[3];
  sq = red[4] + red[5] + red[6] + red[7];
  float mu = s * (1.f / DMOD);
  float rs = rsqrtf(sq * (1.f / DMOD) - mu * mu + 1e-5f);
#pragma unroll
  for (int q = 0; q < 3; ++q) {
    int c = t + q * 256;
    float y = (xr[c] - mu) * rs * g[c] + bta[c];
    oh[(size_t)row * DMOD + c] = (_Float16)y;
  }
}

// =====================================================================
// GEMM: A[M][K](f16) @ (Bh + Bl/1024)[NTOT][K](f16)^T, 2-term split.
// BM x 128 tile, BK=32, TPB/64 waves, global_load_lds, XCD swizzle,
// N-fastest traversal, 2-buffer pipeline, conflict-free LDS swizzle.
// MODE 0: C f32 (opt += R).  MODE 1: silu-gate f16.  MODE 2: split-K
// atomic.  MODE 3: fused qkvg epilogue.
// =====================================================================
template<int BM, int MODE, int TPB>
__global__ __launch_bounds__(TPB) void gemm_bt(const _Float16* __restrict__ Ah,
                                               const _Float16* __restrict__ Bh,
                                               const _Float16* __restrict__ Bl,
                                               float* __restrict__ C,
                                               const float* __restrict__ R,
                                               _Float16* __restrict__ OH,
                                               _Float16* __restrict__ qH,
                                               _Float16* __restrict__ qL,
                                               _Float16* __restrict__ kH,
                                               _Float16* __restrict__ kL,
                                               _Float16* __restrict__ vtb,
                                               _Float16* __restrict__ gb,
                                               const float* __restrict__ ct,
                                               const float* __restrict__ st,
                                               int nbx, int nby, int K, int klen,
                                               int ldc)
{
  constexpr int NW  = TPB / 64;
  constexpr int RPW = 2 * BM / NW;
  constexpr int RI  = RPW / 16;
  constexpr int APW = BM * 64 / NW;
  constexpr int AIS = APW / 1024;
  constexpr int BPW = 8192 / NW;
  constexpr int BIS = BPW / 1024;
  __shared__ char sAh[2][BM * 64];
  __shared__ char sBh[2][8192];
  __shared__ char sBl[2][8192];
  const int tid = threadIdx.x, lane = tid & 63, w = tid >> 6;

  int nwg = gridDim.x, bid = blockIdx.x;
  int qq = nwg >> 3, rr = nwg & 7;
  int xc = bid & 7, ix = bid >> 3;
  int wg = (xc < rr ? xc * (qq + 1) : rr * (qq + 1) + (xc - rr) * qq) + ix;
  int bx = wg % nbx;
  int rem = wg / nbx;
  int by = rem % nby;
  int kbase = (rem / nby) * klen;

  const int m0 = by * BM, n0 = bx * 128;
  const int wm = (w >> 1) * RPW, wn = (w & 1) * 64;
  const int lhi = lane >> 4, llo = lane & 15;

  const f32x4 fz = {0.f, 0.f, 0.f, 0.f};
  f32x4 accH[RI][4], accM[RI][4];
#pragma unroll
  for (int i = 0; i < RI; ++i)
#pragma unroll
    for (int j = 0; j < 4; ++j) { accH[i][j] = fz; accM[i][j] = fz; }

  auto stage = [&](int buf, int k0) {
#pragma unroll
    for (int i = 0; i < AIS; ++i) {           // A plane
      int off = w * APW + i * 1024 + lane * 16;
      int r = off >> 6, c = (off >> 4) & 3;
      size_t go = (size_t)r * K + ((c ^ ((r >> 1) & 3)) << 3);
      GLD16(Ah + (size_t)m0 * K + k0 + go, &sAh[buf][w * APW + i * 1024]);
    }
#pragma unroll
    for (int i = 0; i < BIS; ++i) {           // B planes (hi+lo)
      int off = w * BPW + i * 1024 + lane * 16;
      int r = off >> 6, c = (off >> 4) & 3;
      size_t go = (size_t)r * K + ((c ^ ((r >> 1) & 3)) << 3);
      GLD16(Bh + (size_t)n0 * K + k0 + go, &sBh[buf][w * BPW + i * 1024]);
      GLD16(Bl + (size_t)n0 * K + k0 + go, &sBl[buf][w * BPW + i * 1024]);
    }
  };

  stage(0, kbase);
  asm volatile("s_waitcnt vmcnt(0)" ::: "memory");
  __builtin_amdgcn_s_barrier();

  int cur = 0;
  const int kend = kbase + klen;
  for (int k0 = kbase; k0 < kend; k0 += 32) {
    if (k0 + 32 < kend) stage(cur ^ 1, k0 + 32);

    f16x8 ah[RI], bh[4], bl[4];
#pragma unroll
    for (int r = 0; r < RI; ++r) {
      int ra = wm + r * 16 + llo;
      ah[r] = *(const f16x8*)(&sAh[cur][ra * 64 + ((lhi ^ ((ra >> 1) & 3)) << 4)]);
    }
#pragma unroll
    for (int r = 0; r < 4; ++r) {
      int rb = wn + r * 16 + llo;
      int sb = rb * 64 + ((lhi ^ ((rb >> 1) & 3)) << 4);
      bh[r] = *(const f16x8*)(&sBh[cur][sb]);
      bl[r] = *(const f16x8*)(&sBl[cur][sb]);
    }
#pragma unroll
    for (int i = 0; i < RI; ++i)
#pragma unroll
      for (int j = 0; j < 4; ++j) {
        accH[i][j] = __builtin_amdgcn_mfma_f32_16x16x32_f16(ah[i], bh[j], accH[i][j], 0, 0, 0);
        accM[i][j] = __builtin_amdgcn_mfma_f32_16x16x32_f16(ah[i], bl[j], accM[i][j], 0, 0, 0);
      }

    asm volatile("s_waitcnt vmcnt(0)" ::: "memory");
    __builtin_amdgcn_s_barrier();
    cur ^= 1;
  }

  if constexpr (MODE == 0) {
#pragma unroll
    for (int i = 0; i < RI; ++i)
#pragma unroll
      for (int j = 0; j < 4; ++j)
#pragma unroll
        for (int rg = 0; rg < 4; ++rg) {
          int m = m0 + wm + i * 16 + lhi * 4 + rg;
          int n = n0 + wn + j * 16 + llo;
          size_t idx = (size_t)m * ldc + n;
          float v = accH[i][j][rg] + accM[i][j][rg] * (1.0f / 1024.0f);
          if (R) v += R[idx];
          C[idx] = v;
        }
  } else if constexpr (MODE == 2) {
#pragma unroll
    for (int i = 0; i < RI; ++i)
#pragma unroll
      for (int j = 0; j < 4; ++j)
#pragma unroll
        for (int rg = 0; rg < 4; ++rg) {
          int m = m0 + wm + i * 16 + lhi * 4 + rg;
          int n = n0 + wn + j * 16 + llo;
          float v = accH[i][j][rg] + accM[i][j][rg] * (1.0f / 1024.0f);
          atomicAdd(&C[(size_t)m * ldc + n], v);
        }
  } else if constexpr (MODE == 1) {
#pragma unroll
    for (int i = 0; i < RI; ++i)
#pragma unroll
      for (int j = 0; j < 2; ++j)
#pragma unroll
        for (int rg = 0; rg < 4; ++rg) {
          int m = m0 + wm + i * 16 + lhi * 4 + rg;
          int n = (n0 >> 1) + (wn >> 1) + j * 16 + llo;
          float f1 = accH[i][j][rg]     + accM[i][j][rg]     * (1.0f / 1024.0f);
          float gv = accH[i][j + 2][rg] + accM[i][j + 2][rg] * (1.0f / 1024.0f);
          float y = f1 / (1.f + expf(-f1)) * gv;
          OH[(size_t)m * 3072 + n] = (_Float16)y;
        }
  } else {
    // MODE 3: fused qkvg epilogue (block-uniform region select on n0)
    if (n0 < 1536) {
      bool isq = n0 < 768;
      _Float16* dH = isq ? qH : kH;
      _Float16* dL = isq ? qL : kL;
      int nbase = isq ? n0 : n0 - 768;
#pragma unroll
      for (int i = 0; i < RI; ++i)
#pragma unroll
        for (int j = 0; j < 4; ++j) {
          int n = nbase + wn + j * 16 + llo;
          int h = n >> 6, idk = n & 63, jp = idk >> 1;
          float sgn = (n & 1) ? 1.f : -1.f;
#pragma unroll
          for (int rg = 0; rg < 4; ++rg) {
            int m = m0 + wm + i * 16 + lhi * 4 + rg;
            int s = m & (SEQ - 1), b = m >> 10;
            float v = accH[i][j][rg] + accM[i][j][rg] * (1.0f / 1024.0f);
            float p = __shfl_xor(v, 1);
            float cc = ct[s * 32 + jp], sn = st[s * 32 + jp];
            float r = v * cc + sgn * p * sn;
            _Float16 hh = (_Float16)r;
            size_t dst = ((size_t)(b * NH + h) * SEQ + s) * DKH + idk;
            dH[dst] = hh;
            dL[dst] = (_Float16)((r - (float)hh) * 1024.f);
          }
        }
    } else if (n0 < 3072) {
      int nbase = n0 - 1536;
#pragma unroll
      for (int i = 0; i < RI; ++i) {
        int m = m0 + wm + i * 16 + lhi * 4;
        int s = m & (SEQ - 1), b = m >> 10;
#pragma unroll
        for (int j = 0; j < 4; ++j) {
          int n = nbase + wn + j * 16 + llo;
          int h = n >> 7, d = n & 127;
          f16x4 tv;
#pragma unroll
          for (int rg = 0; rg < 4; ++rg)
            tv[rg] = (_Float16)(accH[i][j][rg] + accM[i][j][rg] * (1.0f / 1024.0f));
          *(f16x4*)(vtb + ((size_t)(b * NH + h) * DVH + d) * SEQ + s) = tv;
        }
      }
    } else {
      int nbase = n0 - 3072;
#pragma unroll
      for (int i = 0; i < RI; ++i)
#pragma unroll
        for (int j = 0; j < 4; ++j) {
          int n = nbase + wn + j * 16 + llo;
#pragma unroll
          for (int rg = 0; rg < 4; ++rg) {
            int m = m0 + wm + i * 16 + lhi * 4 + rg;
            float v = accH[i][j][rg] + accM[i][j][rg] * (1.0f / 1024.0f);
            gb[(size_t)m * DVAL + n] = (_Float16)v;
          }
        }
    }
  }
}

// =====================================================================
// retention stage 1 (split-K chunk=1): per (bh, rb, ct): one QK^T(3-term)
// -> decay -> PV partial; atomicAdd into accbuf and dsacc.
// 36x48 = 1728 uniform blocks — max parallelism (measured scaling law).
// accb/dsacc are pre-zeroed (upfront memset on first use; attn_norm
// re-zeroes after consuming each layer).
// =====================================================================
__global__ __launch_bounds__(256) void attn_part(const _Float16* __restrict__ qrH_,
                                                 const _Float16* __restrict__ qrL_,
                                                 const _Float16* __restrict__ krH_,
                                                 const _Float16* __restrict__ krL_,
                                                 const _Float16* __restrict__ vt,
                                                 float* __restrict__ accb,
                                                 float* __restrict__ dsacc)
{
  static const int RBt[36] = {0,1,1,2,2,2,3,3,3,3,4,4,4,4,4,5,5,5,5,5,5,
                              6,6,6,6,6,6,6,7,7,7,7,7,7,7,7};
  static const int CTt[36] = {0,0,1,0,1,2,0,1,2,3,0,1,2,3,4,0,1,2,3,4,5,
                              0,1,2,3,4,5,6,0,1,2,3,4,5,6,7};
  __shared__ char pbuf[32768];          // 4 waves x [32][128] f16, XOR-swizzled
  const int tid = threadIdx.x, lane = tid & 63, w = tid >> 6;
  const int rb = RBt[blockIdx.x], ctc = CTt[blockIdx.x];
  const int bh = blockIdx.y;            // 0..47
  const int h = bh % NH;
  const int wrow0 = rb * 128 + w * 32;
  const int lhi = lane >> 4, llo = lane & 15;

  const _Float16* qbhH = qrH_ + (size_t)bh * SEQ * DKH;
  const _Float16* qbhL = qrL_ + (size_t)bh * SEQ * DKH;
  const _Float16* kbhH = krH_ + (size_t)bh * SEQ * DKH;
  const _Float16* kbhL = krL_ + (size_t)bh * SEQ * DKH;
  const _Float16* vbh  = vt   + (size_t)bh * DVH * SEQ;

  const float lg = log1pf(-exp2f(-(float)(5 + h)));   // ln(gamma_h)
  const float den_lg = expm1f(lg);                    // gamma - 1

  float invn[2][4];
#pragma unroll
  for (int rf = 0; rf < 2; ++rf)
#pragma unroll
    for (int rg = 0; rg < 4; ++rg) {
      int n = wrow0 + rf * 16 + lhi * 4 + rg;
      float sumD = expm1f((float)(n + 1) * lg) / den_lg;  // (1-g^{n+1})/(1-g)
      invn[rf][rg] = rsqrtf(sumD) * 0.125f;               // fold DK^-0.5
    }

  float gm[8];
#pragma unroll
  for (int fc = 0; fc < 8; ++fc)
    gm[fc] = expf(-(float)(fc * 16 + llo) * lg);

  f16x8 qaH[2][2], qaL[2][2];
#pragma unroll
  for (int rf = 0; rf < 2; ++rf)
#pragma unroll
    for (int kt = 0; kt < 2; ++kt) {
      size_t qo = (size_t)(wrow0 + rf * 16 + llo) * DKH + kt * 32 + lhi * 8;
      qaH[rf][kt] = *(const f16x8*)(qbhH + qo);
      qaL[rf][kt] = *(const f16x8*)(qbhL + qo);
    }

  const f32x4 fz = {0.f, 0.f, 0.f, 0.f};
  f32x4 acc[2][8];
#pragma unroll
  for (int i = 0; i < 2; ++i)
#pragma unroll
    for (int j = 0; j < 8; ++j) acc[i][j] = fz;
  float dsum[2][4] = {{0, 0, 0, 0}, {0, 0, 0, 0}};

  {
    const bool diag = (ctc == rb);
    float fn[2][4];
#pragma unroll
    for (int rf = 0; rf < 2; ++rf)
#pragma unroll
      for (int rg = 0; rg < 4; ++rg) {
        int n = wrow0 + rf * 16 + lhi * 4 + rg;
        fn[rf][rg] = expf((float)(n - ctc * 128) * lg) * invn[rf][rg];
      }

#pragma unroll
    for (int fc = 0; fc < 8; ++fc) {
      f32x4 pH[2] = {fz, fz}, pM[2] = {fz, fz};
#pragma unroll
      for (int kt = 0; kt < 2; ++kt) {
        size_t kro = (size_t)(ctc * 128 + fc * 16 + llo) * DKH + kt * 32 + lhi * 8;
        f16x8 kbH = *(const f16x8*)(kbhH + kro);
        f16x8 kbL = *(const f16x8*)(kbhL + kro);
        pH[0] = __builtin_amdgcn_mfma_f32_16x16x32_f16(qaH[0][kt], kbH, pH[0], 0, 0, 0);
        pH[1] = __builtin_amdgcn_mfma_f32_16x16x32_f16(qaH[1][kt], kbH, pH[1], 0, 0, 0);
        pM[0] = __builtin_amdgcn_mfma_f32_16x16x32_f16(qaL[0][kt], kbH, pM[0], 0, 0, 0);
        pM[1] = __builtin_amdgcn_mfma_f32_16x16x32_f16(qaL[1][kt], kbH, pM[1], 0, 0, 0);
        pM[0] = __builtin_amdgcn_mfma_f32_16x16x32_f16(qaH[0][kt], kbL, pM[0], 0, 0, 0);
        pM[1] = __builtin_amdgcn_mfma_f32_16x16x32_f16(qaH[1][kt], kbL, pM[1], 0, 0, 0);
      }
#pragma unroll
      for (int rf = 0; rf < 2; ++rf)
#pragma unroll
        for (int rg = 0; rg < 4; ++rg) {
          float pv = (pH[rf][rg] + pM[rf][rg] * (1.f / 1024.f)) * fn[rf][rg] * gm[fc];
          if (diag) {
            int e = (wrow0 + rf * 16 + lhi * 4 + rg) - (ctc * 128 + fc * 16 + llo);
            if (e < 0) pv = 0.f;
          }
          dsum[rf][rg] += fabsf(pv);
          int prow = rf * 16 + lhi * 4 + rg;
          int byte = (w << 13) + prow * 256 + (fc * 16 + llo) * 2;
          byte ^= (prow & 7) << 4;
          *(_Float16*)(pbuf + byte) = (_Float16)pv;
        }
    }
    // each wave reads only its own pbuf slice — no barrier needed

    f16x8 pa[2][4];
#pragma unroll
    for (int rf2 = 0; rf2 < 2; ++rf2)
#pragma unroll
      for (int kt = 0; kt < 4; ++kt) {
        int prow = rf2 * 16 + llo;
        int byte = (w << 13) + prow * 256 + kt * 64 + lhi * 16;
        byte ^= (prow & 7) << 4;
        pa[rf2][kt] = *(const f16x8*)(pbuf + byte);
      }
#pragma unroll
    for (int fd = 0; fd < 8; ++fd)
#pragma unroll
      for (int kt = 0; kt < 4; ++kt) {
        f16x8 vb = *(const f16x8*)(vbh + (size_t)(fd * 16 + llo) * SEQ + ctc * 128 + kt * 32 + lhi * 8);
        acc[0][fd] = __builtin_amdgcn_mfma_f32_16x16x32_f16(pa[0][kt], vb, acc[0][fd], 0, 0, 0);
        acc[1][fd] = __builtin_amdgcn_mfma_f32_16x16x32_f16(pa[1][kt], vb, acc[1][fd], 0, 0, 0);
      }
  }

  float* ab = accb + (size_t)bh * SEQ * DVH;
#pragma unroll
  for (int rf = 0; rf < 2; ++rf)
#pragma unroll
    for (int rg = 0; rg < 4; ++rg) {
      float d = dsum[rf][rg];
      d += __shfl_xor(d, 1); d += __shfl_xor(d, 2);
      d += __shfl_xor(d, 4); d += __shfl_xor(d, 8);
      int row = wrow0 + rf * 16 + lhi * 4 + rg;
      if (llo == 0) atomicAdd(&dsacc[bh * SEQ + row], d);
#pragma unroll
      for (int fd = 0; fd < 8; ++fd)
        atomicAdd(&ab[(size_t)row * DVH + fd * 16 + llo], acc[rf][fd][rg]);
    }
}

// =====================================================================
// retention stage 2: row-normalize + group-norm + silu(g)*o fused,
// g read as f16 dense [row][1536]; writes ogb f16 [B*S][1536].
// ALSO re-zeroes accb/dsacc after consuming (each element owned by
// exactly one thread) so the next layer's atomics start from 0 —
// replaces the per-layer memset dispatch.
// =====================================================================
__global__ __launch_bounds__(256) void attn_norm(float* __restrict__ accb,
                                                 float* __restrict__ dsacc,
                                                 const _Float16* __restrict__ gsrc,
                                                 _Float16* __restrict__ oh)
{
  int bh = blockIdx.y, h = bh % NH, b = bh / NH;
  int s0 = blockIdx.x * 32;
  int lane = threadIdx.x & 63, w = threadIdx.x >> 6;
  float* ab = accb + ((size_t)bh * SEQ + s0) * DVH;
#pragma unroll
  for (int i = 0; i < 8; ++i) {
    int r = w * 8 + i;
    size_t row = (size_t)(b * SEQ + s0 + r);
    float2 v = *(const float2*)(ab + (size_t)r * DVH + lane * 2);
    float inv = 1.f / fmaxf(dsacc[bh * SEQ + s0 + r], 1.f);
    // consume-and-clear: next layer's atomics need zeroed buffers
    float2 zz = {0.f, 0.f};
    *(float2*)(ab + (size_t)r * DVH + lane * 2) = zz;
    if (lane == 0 && w == 0 && i == 0) { /* no-op placeholder */ }
    v.x *= inv; v.y *= inv;
    float ss = v.x * v.x + v.y * v.y;
#pragma unroll
    for (int m = 1; m < 64; m <<= 1) ss += __shfl_xor(ss, m);
    float rs = rsqrtf(ss * (1.f / 128.f) + 1e-5f);
    float o0 = v.x * rs, o1 = v.y * rs;
    f16x2 gg = *(const f16x2*)(gsrc + row * DVAL + h * DVH + lane * 2);
    float gx = (float)gg[0], gy = (float)gg[1];
    float y0 = gx / (1.f + expf(-gx)) * o0;
    float y1 = gy / (1.f + expf(-gy)) * o1;
    f16x2 vh = {(_Float16)y0, (_Float16)y1};
    *(f16x2*)(oh + row * DVAL + h * DVH + lane * 2) = vh;
    if (lane == 0) dsacc[bh * SEQ + s0 + r] = 0.f;
  }
}

// =====================================================================
// mean pool over S
// =====================================================================
__global__ void pool_kernel(const float* __restrict__ xf, float* __restrict__ pooled)
{
  int d = blockIdx.x * 256 + threadIdx.x;   // grid.x = 3
  int b = blockIdx.y;
  float acc = 0.f;
  for (int s = 0; s < SEQ; ++s) acc += xf[((size_t)(b * SEQ + s)) * DMOD + d];
  pooled[b * DMOD + d] = acc * (1.f / SEQ);
}

// =====================================================================
// classifier
// =====================================================================
__global__ void clf_kernel(const float* __restrict__ pooled, const float* __restrict__ cw,
                           const float* __restrict__ cb, float* __restrict__ out)
{
  int b = blockIdx.x, c = threadIdx.x;
  if (c < 100) {
    float acc = cb[c];
    for (int d = 0; d < DMOD; ++d) acc += pooled[b * DMOD + d] * cw[d * 100 + c];
    out[b * 100 + c] = acc;
  }
}

// =====================================================================
// host
// =====================================================================
extern "C" void kernel_launch(void* const* d_in, const int* in_sizes, int n_in,
                              void* d_out, int out_size, void* d_ws, size_t ws_size,
                              hipStream_t stream)
{
  const int*   ids  = (const int*)d_in[0];
  const float* emb  = (const float*)d_in[1];
  const float* wq   = (const float*)d_in[2];
  const float* wk   = (const float*)d_in[3];
  const float* wv   = (const float*)d_in[4];
  const float* wg   = (const float*)d_in[5];
  const float* wo   = (const float*)d_in[6];
  const float* ln1g = (const float*)d_in[7];
  const float* ln1b = (const float*)d_in[8];
  const float* ln2g = (const float*)d_in[9];
  const float* ln2b = (const float*)d_in[10];
  const float* fc1  = (const float*)d_in[11];
  const float* gate = (const float*)d_in[12];
  const float* fc2  = (const float*)d_in[13];
  const float* lnfg = (const float*)d_in[14];
  const float* lnfb = (const float*)d_in[15];
  const float* clfw = (const float*)d_in[16];
  const float* clfb = (const float*)d_in[17];
  float* out = (float*)d_out;

  char* ws = (char*)d_ws;
  size_t off = 0;
  auto alloc = [&](size_t bytes) {
    size_t r = off;
    off = (off + bytes + 255) & ~(size_t)255;
    return r;
  };

  const size_t W_QKVG = 12ull * 4608 * 768 * 2;
  const size_t W_O    = 12ull * 768 * 1536 * 2;
  const size_t W_F1GT = 12ull * 6144 * 768 * 2;
  const size_t W_F2   = 12ull * 768 * 3072 * 2;
  const bool big = ws_size >= 720ull * 1024 * 1024;
  const size_t d12 = big ? 1 : 12;

  _Float16* wQKVGh = (_Float16*)(ws + alloc(W_QKVG / d12));
  _Float16* wQKVGl = (_Float16*)(ws + alloc(W_QKVG / d12));
  _Float16* wOh    = (_Float16*)(ws + alloc(W_O    / d12));
  _Float16* wOl    = (_Float16*)(ws + alloc(W_O    / d12));
  _Float16* wF1GTh = (_Float16*)(ws + alloc(W_F1GT / d12));
  _Float16* wF1GTl = (_Float16*)(ws + alloc(W_F1GT / d12));
  _Float16* wF2h   = (_Float16*)(ws + alloc(W_F2   / d12));
  _Float16* wF2l   = (_Float16*)(ws + alloc(W_F2   / d12));

  float*    x    = (float*)(ws + alloc((size_t)BS * DMOD * 4));
  _Float16* hbfH = (_Float16*)(ws + alloc((size_t)BS * DMOD * 2));
  float*    cbuf = (float*)(ws + alloc((size_t)BS * DMOD * 4));   // final-LN scratch
  char*     regB = ws + alloc(8ull * 6291456);                    // 50.3 MB
  float*    accb = (float*)(ws + alloc((size_t)BS * DVAL * 4 + 48ull * SEQ * 4));
  float*    dsacc = accb + (size_t)BS * DVAL;
  float*    ctab = (float*)(ws + alloc(1024 * 32 * 4));
  float*    stab = (float*)(ws + alloc(1024 * 32 * 4));
  float*    pooled = (float*)(ws + alloc(4 * DMOD * 4));

  _Float16* qrbH = (_Float16*)regB;
  _Float16* qrbL = (_Float16*)(regB + 6291456);
  _Float16* krbH = (_Float16*)(regB + 12582912);
  _Float16* krbL = (_Float16*)(regB + 18874368);
  _Float16* vtb  = (_Float16*)(regB + 25165824);
  _Float16* gbuf = (_Float16*)(regB + 37748736);    // 12.58 MB, after vtb
  _Float16* ogbH = (_Float16*)regB;                 // alias (post-attn_part)
  _Float16* ffnbH = (_Float16*)regB;                // alias (post-wo)

  dim3 tb(32, 8);
  const long lsDD = 768l * 768, lsDV = 768l * 1536, lsDF = 768l * 3072;
  const long oQKVG = 4608l * 768, oO = 768l * 1536, oF1 = 6144l * 768, oF2 = 768l * 3072;

  trig_kernel<<<1024, 32, 0, stream>>>(ctab, stab);
  // one upfront clear (handles 0xAA poison); attn_norm re-zeroes per layer
  hipMemsetAsync(accb, 0, (size_t)BS * DVAL * 4 + 48ull * SEQ * 4, stream);

  if (big) {
    wcvt_kernel<<<dim3(24, 24, 12), tb, 0, stream>>>(wq,   wQKVGh, wQKVGl, 768, 768,  lsDD, oQKVG, 0,    0);
    wcvt_kernel<<<dim3(24, 24, 12), tb, 0, stream>>>(wk,   wQKVGh, wQKVGl, 768, 768,  lsDD, oQKVG, 768,  0);
    wcvt_kernel<<<dim3(48, 24, 12), tb, 0, stream>>>(wv,   wQKVGh, wQKVGl, 768, 1536, lsDV, oQKVG, 1536, 0);
    wcvt_kernel<<<dim3(48, 24, 12), tb, 0, stream>>>(wg,   wQKVGh, wQKVGl, 768, 1536, lsDV, oQKVG, 3072, 0);
    wcvt_kernel<<<dim3(24, 48, 12), tb, 0, stream>>>(wo,   wOh,    wOl,    1536, 768, lsDV, oO,    0,    0);
    wcvt_kernel<<<dim3(96, 24, 12), tb, 0, stream>>>(fc1,  wF1GTh, wF1GTl, 768, 3072, lsDF, oF1,   0,    1);
    wcvt_kernel<<<dim3(96, 24, 12), tb, 0, stream>>>(gate, wF1GTh, wF1GTl, 768, 3072, lsDF, oF1,   0,    2);
    wcvt_kernel<<<dim3(24, 96, 12), tb, 0, stream>>>(fc2,  wF2h,   wF2l,   3072, 768, lsDF, oF2,   0,    0);
  }

  embed_kernel<<<BS, 192, 0, stream>>>(ids, emb, x);

  for (int l = 0; l < 12; ++l) {
    const _Float16 *Wqkh, *Wqkl, *Woh_, *Wol_, *Wfh, *Wfl, *W2h, *W2l;
    if (big) {
      Wqkh = wQKVGh + (size_t)l * oQKVG;  Wqkl = wQKVGl + (size_t)l * oQKVG;
      Woh_ = wOh    + (size_t)l * oO;     Wol_ = wOl    + (size_t)l * oO;
      Wfh  = wF1GTh + (size_t)l * oF1;    Wfl  = wF1GTl + (size_t)l * oF1;
      W2h  = wF2h   + (size_t)l * oF2;    W2l  = wF2l   + (size_t)l * oF2;
    } else {
      wcvt_kernel<<<dim3(24, 24, 1), tb, 0, stream>>>(wq   + (size_t)l * lsDD, wQKVGh, wQKVGl, 768, 768,  0, 0, 0,    0);
      wcvt_kernel<<<dim3(24, 24, 1), tb, 0, stream>>>(wk   + (size_t)l * lsDD, wQKVGh, wQKVGl, 768, 768,  0, 0, 768,  0);
      wcvt_kernel<<<dim3(48, 24, 1), tb, 0, stream>>>(wv   + (size_t)l * lsDV, wQKVGh, wQKVGl, 768, 1536, 0, 0, 1536, 0);
      wcvt_kernel<<<dim3(48, 24, 1), tb, 0, stream>>>(wg   + (size_t)l * lsDV, wQKVGh, wQKVGl, 768, 1536, 0, 0, 3072, 0);
      wcvt_kernel<<<dim3(24, 48, 1), tb, 0, stream>>>(wo   + (size_t)l * lsDV, wOh,    wOl,    1536, 768, 0, 0, 0,    0);
      wcvt_kernel<<<dim3(96, 24, 1), tb, 0, stream>>>(fc1  + (size_t)l * lsDF, wF1GTh, wF1GTl, 768, 3072, 0, 0, 0,    1);
      wcvt_kernel<<<dim3(96, 24, 1), tb, 0, stream>>>(gate + (size_t)l * lsDF, wF1GTh, wF1GTl, 768, 3072, 0, 0, 0,    2);
      wcvt_kernel<<<dim3(24, 96, 1), tb, 0, stream>>>(fc2  + (size_t)l * lsDF, wF2h,   wF2l,   3072, 768, 0, 0, 0,    0);
      Wqkh = wQKVGh; Wqkl = wQKVGl; Woh_ = wOh; Wol_ = wOl;
      Wfh = wF1GTh; Wfl = wF1GTl; W2h = wF2h; W2l = wF2l;
    }

    ln_h_kernel<<<BS, 256, 0, stream>>>(x, ln1g + l * 768, ln1b + l * 768, hbfH);
    // fused qkvg: 256x128 tile, 8 waves
    gemm_bt<256, 3, 512><<<36 * 16, 512, 0, stream>>>(hbfH, Wqkh, Wqkl, nullptr, nullptr,
                                                      nullptr, qrbH, qrbL, krbH, krbL,
                                                      vtb, gbuf, ctab, stab,
                                                      36, 16, 768, 768, 0);
    attn_part<<<dim3(36, 48), 256, 0, stream>>>(qrbH, qrbL, krbH, krbL, vtb, accb, dsacc);
    attn_norm<<<dim3(32, 48), 256, 0, stream>>>(accb, dsacc, gbuf, ogbH);
    // wo: split-K x2, partials atomically accumulate into x (holds residual)
    gemm_bt<64, 2, 256><<<6 * 64 * 2, 256, 0, stream>>>(ogbH, Woh_, Wol_, x, nullptr,
                                                        nullptr, nullptr, nullptr, nullptr,
                                                        nullptr, nullptr, nullptr, nullptr,
                                                        nullptr, 6, 64, 1536, 768, 768);
    ln_h_kernel<<<BS, 256, 0, stream>>>(x, ln2g + l * 768, ln2b + l * 768, hbfH);
    // f1gt: 256x128 tile, 8 waves, fused silu-gate epilogue
    gemm_bt<256, 1, 512><<<48 * 16, 512, 0, stream>>>(hbfH, Wfh, Wfl, nullptr, nullptr,
                                                      ffnbH, nullptr, nullptr, nullptr,
                                                      nullptr, nullptr, nullptr, nullptr,
                                                      nullptr, 48, 16, 768, 768, 0);
    // f2: split-K x4
    gemm_bt<64, 2, 256><<<6 * 64 * 4, 256, 0, stream>>>(ffnbH, W2h, W2l, x, nullptr,
                                                        nullptr, nullptr, nullptr, nullptr,
                                                        nullptr, nullptr, nullptr, nullptr,
                                                        nullptr, 6, 64, 3072, 768, 768);
  }

  float* xf = cbuf;
  ln_kernel<<<BS, 256, 0, stream>>>(x, lnfg, lnfb, xf);
  pool_kernel<<<dim3(3, 4), 256, 0, stream>>>(xf, pooled);
  clf_kernel<<<4, 128, 0, stream>>>(pooled, clfw, clfb, out);
}

// Round 22
// 6004.200 us; speedup vs baseline: 1.1668x; 1.0010x over previous
//
#include <hip/hip_runtime.h>
#include <cstdint>
#include <cstddef>

// ---------- types ----------
typedef float     f32x4 __attribute__((ext_vector_type(4)));
typedef _Float16  f16x8 __attribute__((ext_vector_type(8)));
typedef _Float16  f16x4 __attribute__((ext_vector_type(4)));
typedef _Float16  f16x2 __attribute__((ext_vector_type(2)));

#define GLD16(g, l)                                                            \
  __builtin_amdgcn_global_load_lds(                                           \
      (const __attribute__((address_space(1))) void*)(g),                     \
      (__attribute__((address_space(3))) void*)(l), 16, 0, 0)

// ---------- constants ----------
#define BQ    4
#define SEQ   1024
#define DMOD  768
#define NH    12
#define DKH   64
#define DVH   128
#define DVAL  1536
#define DFFN  3072
#define BS    4096   /* BQ*SEQ */

// =====================================================================
// theta-shift trig table: ct/st[s][jp], jp=0..31
// =====================================================================
__global__ void trig_kernel(float* __restrict__ ct, float* __restrict__ st)
{
  int s = blockIdx.x, jp = threadIdx.x;   // 1024 x 32
  float ang = exp2f(-(float)jp * (13.287712379549449f / 31.f));
  float a = (float)s * ang;
  ct[s * 32 + jp] = cosf(a);
  st[s * 32 + jp] = sinf(a);
}

// =====================================================================
// weight transpose + f32->f16 hi/lo split into fused layout.
// mode 0: orow = row_off + n  (linear)
// mode 1: fc1 interleave : orow = (n>>6)*128 + ((n>>5)&1)*64 + (n&31)
// mode 2: gate interleave: orow = (n>>6)*128 + ((n>>5)&1)*64 + 32 + (n&31)
// =====================================================================
__global__ void wcvt_kernel(const float* __restrict__ win, _Float16* __restrict__ whi,
                            _Float16* __restrict__ wlo, int K, int N,
                            long in_ls, long out_ls, int row_off, int mode)
{
  __shared__ float tle[32][33];
  size_t ib = (size_t)blockIdx.z * in_ls;
  size_t ob = (size_t)blockIdx.z * out_ls;
  int k0 = blockIdx.y * 32, n0 = blockIdx.x * 32;
  int tx = threadIdx.x, ty = threadIdx.y;
#pragma unroll
  for (int i = 0; i < 4; ++i)
    tle[ty + 8*i][tx] = win[ib + (size_t)(k0 + ty + 8*i) * N + n0 + tx];
  __syncthreads();
#pragma unroll
  for (int i = 0; i < 4; ++i) {
    float v = tle[tx][ty + 8*i];
    _Float16 h = (_Float16)v;
    int n = n0 + ty + 8*i;
    int orow;
    if (mode == 0)      orow = row_off + n;
    else if (mode == 1) orow = (n >> 6) * 128 + ((n >> 5) & 1) * 64 + (n & 31);
    else                orow = (n >> 6) * 128 + ((n >> 5) & 1) * 64 + 32 + (n & 31);
    size_t idx = ob + (size_t)orow * K + k0 + tx;
    whi[idx] = h;
    wlo[idx] = (_Float16)((v - (float)h) * 1024.0f);
  }
}

// =====================================================================
// embedding gather
// =====================================================================
__global__ void embed_kernel(const int* __restrict__ ids, const float* __restrict__ emb,
                             float* __restrict__ x)
{
  int tok = blockIdx.x;
  int id  = ids[tok];
  const float4* s = (const float4*)(emb + (size_t)id * DMOD);
  float4*       d = (float4*)(x + (size_t)tok * DMOD);
  d[threadIdx.x] = s[threadIdx.x];   // block = 192 threads
}

// =====================================================================
// layernorm over 768 -> f32 out (final LN)
// =====================================================================
__global__ __launch_bounds__(256) void ln_kernel(const float* __restrict__ x,
                                                 const float* __restrict__ g,
                                                 const float* __restrict__ bta,
                                                 float* __restrict__ out)
{
  int row = blockIdx.x;
  const float* xr = x + (size_t)row * DMOD;
  int t = threadIdx.x;
  float v0 = xr[t], v1 = xr[t + 256], v2 = xr[t + 512];
  float s  = v0 + v1 + v2;
  float sq = v0*v0 + v1*v1 + v2*v2;
#pragma unroll
  for (int m = 1; m < 64; m <<= 1) { s += __shfl_xor(s, m); sq += __shfl_xor(sq, m); }
  __shared__ float red[8];
  int wv = t >> 6, ln_ = t & 63;
  if (ln_ == 0) { red[wv] = s; red[wv + 4] = sq; }
  __syncthreads();
  s  = red[0] + red[1] + red[2] + red[3];
  sq = red[4] + red[5] + red[6] + red[7];
  float mu = s * (1.f / DMOD);
  float rs = rsqrtf(sq * (1.f / DMOD) - mu * mu + 1e-5f);
  out[(size_t)row * DMOD + t      ] = (v0 - mu) * rs * g[t      ] + bta[t      ];
  out[(size_t)row * DMOD + t + 256] = (v1 - mu) * rs * g[t + 256] + bta[t + 256];
  out[(size_t)row * DMOD + t + 512] = (v2 - mu) * rs * g[t + 512] + bta[t + 512];
}

// =====================================================================
// layernorm over 768 -> f16 (GEMM A-operand)
// =====================================================================
__global__ __launch_bounds__(256) void ln_h_kernel(const float* __restrict__ x,
                                                   const float* __restrict__ g,
                                                   const float* __restrict__ bta,
                                                   _Float16* __restrict__ oh)
{
  int row = blockIdx.x;
  const float* xr = x + (size_t)row * DMOD;
  int t = threadIdx.x;
  float v0 = xr[t], v1 = xr[t + 256], v2 = xr[t + 512];
  float s  = v0 + v1 + v2;
  float sq = v0*v0 + v1*v1 + v2*v2;
#pragma unroll
  for (int m = 1; m < 64; m <<= 1) { s += __shfl_xor(s, m); sq += __shfl_xor(sq, m); }
  __shared__ float red[8];
  int wv = t >> 6, ln_ = t & 63;
  if (ln_ == 0) { red[wv] = s; red[wv + 4] = sq; }
  __syncthreads();
  s  = red[0] + red[1] + red[2] + red[3];
  sq = red[4] + red[5] + red[6] + red[7];
  float mu = s * (1.f / DMOD);
  float rs = rsqrtf(sq * (1.f / DMOD) - mu * mu + 1e-5f);
#pragma unroll
  for (int q = 0; q < 3; ++q) {
    int c = t + q * 256;
    float y = (xr[c] - mu) * rs * g[c] + bta[c];
    oh[(size_t)row * DMOD + c] = (_Float16)y;
  }
}

// =====================================================================
// GEMM: A[M][K](f16) @ (Bh + Bl/1024)[NTOT][K](f16)^T, 2-term split.
// BM x 128 tile, BK=32, TPB/64 waves, global_load_lds, XCD swizzle,
// N-fastest traversal, 2-buffer pipeline, conflict-free LDS swizzle.
// MODE 0: C f32 (opt += R).  MODE 1: silu-gate f16.  MODE 2: split-K
// atomic.  MODE 3: fused qkvg epilogue.
// =====================================================================
template<int BM, int MODE, int TPB>
__global__ __launch_bounds__(TPB) void gemm_bt(const _Float16* __restrict__ Ah,
                                               const _Float16* __restrict__ Bh,
                                               const _Float16* __restrict__ Bl,
                                               float* __restrict__ C,
                                               const float* __restrict__ R,
                                               _Float16* __restrict__ OH,
                                               _Float16* __restrict__ qH,
                                               _Float16* __restrict__ qL,
                                               _Float16* __restrict__ kH,
                                               _Float16* __restrict__ kL,
                                               _Float16* __restrict__ vtb,
                                               _Float16* __restrict__ gb,
                                               const float* __restrict__ ct,
                                               const float* __restrict__ st,
                                               int nbx, int nby, int K, int klen,
                                               int ldc)
{
  constexpr int NW  = TPB / 64;
  constexpr int RPW = 2 * BM / NW;
  constexpr int RI  = RPW / 16;
  constexpr int APW = BM * 64 / NW;
  constexpr int AIS = APW / 1024;
  constexpr int BPW = 8192 / NW;
  constexpr int BIS = BPW / 1024;
  __shared__ char sAh[2][BM * 64];
  __shared__ char sBh[2][8192];
  __shared__ char sBl[2][8192];
  const int tid = threadIdx.x, lane = tid & 63, w = tid >> 6;

  int nwg = gridDim.x, bid = blockIdx.x;
  int qq = nwg >> 3, rr = nwg & 7;
  int xc = bid & 7, ix = bid >> 3;
  int wg = (xc < rr ? xc * (qq + 1) : rr * (qq + 1) + (xc - rr) * qq) + ix;
  int bx = wg % nbx;
  int rem = wg / nbx;
  int by = rem % nby;
  int kbase = (rem / nby) * klen;

  const int m0 = by * BM, n0 = bx * 128;
  const int wm = (w >> 1) * RPW, wn = (w & 1) * 64;
  const int lhi = lane >> 4, llo = lane & 15;

  const f32x4 fz = {0.f, 0.f, 0.f, 0.f};
  f32x4 accH[RI][4], accM[RI][4];
#pragma unroll
  for (int i = 0; i < RI; ++i)
#pragma unroll
    for (int j = 0; j < 4; ++j) { accH[i][j] = fz; accM[i][j] = fz; }

  auto stage = [&](int buf, int k0) {
#pragma unroll
    for (int i = 0; i < AIS; ++i) {           // A plane
      int off = w * APW + i * 1024 + lane * 16;
      int r = off >> 6, c = (off >> 4) & 3;
      size_t go = (size_t)r * K + ((c ^ ((r >> 1) & 3)) << 3);
      GLD16(Ah + (size_t)m0 * K + k0 + go, &sAh[buf][w * APW + i * 1024]);
    }
#pragma unroll
    for (int i = 0; i < BIS; ++i) {           // B planes (hi+lo)
      int off = w * BPW + i * 1024 + lane * 16;
      int r = off >> 6, c = (off >> 4) & 3;
      size_t go = (size_t)r * K + ((c ^ ((r >> 1) & 3)) << 3);
      GLD16(Bh + (size_t)n0 * K + k0 + go, &sBh[buf][w * BPW + i * 1024]);
      GLD16(Bl + (size_t)n0 * K + k0 + go, &sBl[buf][w * BPW + i * 1024]);
    }
  };

  stage(0, kbase);
  asm volatile("s_waitcnt vmcnt(0)" ::: "memory");
  __builtin_amdgcn_s_barrier();

  int cur = 0;
  const int kend = kbase + klen;
  for (int k0 = kbase; k0 < kend; k0 += 32) {
    if (k0 + 32 < kend) stage(cur ^ 1, k0 + 32);

    f16x8 ah[RI], bh[4], bl[4];
#pragma unroll
    for (int r = 0; r < RI; ++r) {
      int ra = wm + r * 16 + llo;
      ah[r] = *(const f16x8*)(&sAh[cur][ra * 64 + ((lhi ^ ((ra >> 1) & 3)) << 4)]);
    }
#pragma unroll
    for (int r = 0; r < 4; ++r) {
      int rb = wn + r * 16 + llo;
      int sb = rb * 64 + ((lhi ^ ((rb >> 1) & 3)) << 4);
      bh[r] = *(const f16x8*)(&sBh[cur][sb]);
      bl[r] = *(const f16x8*)(&sBl[cur][sb]);
    }
#pragma unroll
    for (int i = 0; i < RI; ++i)
#pragma unroll
      for (int j = 0; j < 4; ++j) {
        accH[i][j] = __builtin_amdgcn_mfma_f32_16x16x32_f16(ah[i], bh[j], accH[i][j], 0, 0, 0);
        accM[i][j] = __builtin_amdgcn_mfma_f32_16x16x32_f16(ah[i], bl[j], accM[i][j], 0, 0, 0);
      }

    asm volatile("s_waitcnt vmcnt(0)" ::: "memory");
    __builtin_amdgcn_s_barrier();
    cur ^= 1;
  }

  if constexpr (MODE == 0) {
#pragma unroll
    for (int i = 0; i < RI; ++i)
#pragma unroll
      for (int j = 0; j < 4; ++j)
#pragma unroll
        for (int rg = 0; rg < 4; ++rg) {
          int m = m0 + wm + i * 16 + lhi * 4 + rg;
          int n = n0 + wn + j * 16 + llo;
          size_t idx = (size_t)m * ldc + n;
          float v = accH[i][j][rg] + accM[i][j][rg] * (1.0f / 1024.0f);
          if (R) v += R[idx];
          C[idx] = v;
        }
  } else if constexpr (MODE == 2) {
#pragma unroll
    for (int i = 0; i < RI; ++i)
#pragma unroll
      for (int j = 0; j < 4; ++j)
#pragma unroll
        for (int rg = 0; rg < 4; ++rg) {
          int m = m0 + wm + i * 16 + lhi * 4 + rg;
          int n = n0 + wn + j * 16 + llo;
          float v = accH[i][j][rg] + accM[i][j][rg] * (1.0f / 1024.0f);
          atomicAdd(&C[(size_t)m * ldc + n], v);
        }
  } else if constexpr (MODE == 1) {
#pragma unroll
    for (int i = 0; i < RI; ++i)
#pragma unroll
      for (int j = 0; j < 2; ++j)
#pragma unroll
        for (int rg = 0; rg < 4; ++rg) {
          int m = m0 + wm + i * 16 + lhi * 4 + rg;
          int n = (n0 >> 1) + (wn >> 1) + j * 16 + llo;
          float f1 = accH[i][j][rg]     + accM[i][j][rg]     * (1.0f / 1024.0f);
          float gv = accH[i][j + 2][rg] + accM[i][j + 2][rg] * (1.0f / 1024.0f);
          float y = f1 / (1.f + expf(-f1)) * gv;
          OH[(size_t)m * 3072 + n] = (_Float16)y;
        }
  } else {
    // MODE 3: fused qkvg epilogue (block-uniform region select on n0)
    if (n0 < 1536) {
      bool isq = n0 < 768;
      _Float16* dH = isq ? qH : kH;
      _Float16* dL = isq ? qL : kL;
      int nbase = isq ? n0 : n0 - 768;
#pragma unroll
      for (int i = 0; i < RI; ++i)
#pragma unroll
        for (int j = 0; j < 4; ++j) {
          int n = nbase + wn + j * 16 + llo;
          int h = n >> 6, idk = n & 63, jp = idk >> 1;
          float sgn = (n & 1) ? 1.f : -1.f;
#pragma unroll
          for (int rg = 0; rg < 4; ++rg) {
            int m = m0 + wm + i * 16 + lhi * 4 + rg;
            int s = m & (SEQ - 1), b = m >> 10;
            float v = accH[i][j][rg] + accM[i][j][rg] * (1.0f / 1024.0f);
            float p = __shfl_xor(v, 1);
            float cc = ct[s * 32 + jp], sn = st[s * 32 + jp];
            float r = v * cc + sgn * p * sn;
            _Float16 hh = (_Float16)r;
            size_t dst = ((size_t)(b * NH + h) * SEQ + s) * DKH + idk;
            dH[dst] = hh;
            dL[dst] = (_Float16)((r - (float)hh) * 1024.f);
          }
        }
    } else if (n0 < 3072) {
      int nbase = n0 - 1536;
#pragma unroll
      for (int i = 0; i < RI; ++i) {
        int m = m0 + wm + i * 16 + lhi * 4;
        int s = m & (SEQ - 1), b = m >> 10;
#pragma unroll
        for (int j = 0; j < 4; ++j) {
          int n = nbase + wn + j * 16 + llo;
          int h = n >> 7, d = n & 127;
          f16x4 tv;
#pragma unroll
          for (int rg = 0; rg < 4; ++rg)
            tv[rg] = (_Float16)(accH[i][j][rg] + accM[i][j][rg] * (1.0f / 1024.0f));
          *(f16x4*)(vtb + ((size_t)(b * NH + h) * DVH + d) * SEQ + s) = tv;
        }
      }
    } else {
      int nbase = n0 - 3072;
#pragma unroll
      for (int i = 0; i < RI; ++i)
#pragma unroll
        for (int j = 0; j < 4; ++j) {
          int n = nbase + wn + j * 16 + llo;
#pragma unroll
          for (int rg = 0; rg < 4; ++rg) {
            int m = m0 + wm + i * 16 + lhi * 4 + rg;
            float v = accH[i][j][rg] + accM[i][j][rg] * (1.0f / 1024.0f);
            gb[(size_t)m * DVAL + n] = (_Float16)v;
          }
        }
    }
  }
}

// =====================================================================
// retention stage 1 (split-K chunk=1): per (bh, rb, ct): one QK^T(3-term)
// -> decay -> PV partial; atomicAdd into accbuf and dsacc.
// 1D grid 1728 blocks, XCD-GROUPED: inverse round-robin maps each XCD to
// 6 complete bh tile-sets (786 KB/bh, L2-resident) -> K/V/Q reuse in the
// XCD's private L2 instead of re-fetching.
// =====================================================================
__global__ __launch_bounds__(256) void attn_part(const _Float16* __restrict__ qrH_,
                                                 const _Float16* __restrict__ qrL_,
                                                 const _Float16* __restrict__ krH_,
                                                 const _Float16* __restrict__ krL_,
                                                 const _Float16* __restrict__ vt,
                                                 float* __restrict__ accb,
                                                 float* __restrict__ dsacc)
{
  static const int RBt[36] = {0,1,1,2,2,2,3,3,3,3,4,4,4,4,4,5,5,5,5,5,5,
                              6,6,6,6,6,6,6,7,7,7,7,7,7,7,7};
  static const int CTt[36] = {0,0,1,0,1,2,0,1,2,3,0,1,2,3,4,0,1,2,3,4,5,
                              0,1,2,3,4,5,6,0,1,2,3,4,5,6,7};
  __shared__ char pbuf[32768];          // 4 waves x [32][128] f16, XOR-swizzled
  const int tid = threadIdx.x, lane = tid & 63, w = tid >> 6;

  // XCD-grouped mapping: 1728 = 8 XCDs x 216; each XCD gets 6 full bh sets
  int bid = blockIdx.x;
  int xc = bid & 7, ix = bid >> 3;
  int wg = xc * 216 + ix;
  const int bh = wg / 36;               // 0..47
  int tix = wg - bh * 36;
  const int rb = RBt[tix], ctc = CTt[tix];
  const int h = bh % NH;
  const int wrow0 = rb * 128 + w * 32;
  const int lhi = lane >> 4, llo = lane & 15;

  const _Float16* qbhH = qrH_ + (size_t)bh * SEQ * DKH;
  const _Float16* qbhL = qrL_ + (size_t)bh * SEQ * DKH;
  const _Float16* kbhH = krH_ + (size_t)bh * SEQ * DKH;
  const _Float16* kbhL = krL_ + (size_t)bh * SEQ * DKH;
  const _Float16* vbh  = vt   + (size_t)bh * DVH * SEQ;

  const float lg = log1pf(-exp2f(-(float)(5 + h)));   // ln(gamma_h)
  const float den_lg = expm1f(lg);                    // gamma - 1

  float invn[2][4];
#pragma unroll
  for (int rf = 0; rf < 2; ++rf)
#pragma unroll
    for (int rg = 0; rg < 4; ++rg) {
      int n = wrow0 + rf * 16 + lhi * 4 + rg;
      float sumD = expm1f((float)(n + 1) * lg) / den_lg;  // (1-g^{n+1})/(1-g)
      invn[rf][rg] = rsqrtf(sumD) * 0.125f;               // fold DK^-0.5
    }

  float gm[8];
#pragma unroll
  for (int fc = 0; fc < 8; ++fc)
    gm[fc] = expf(-(float)(fc * 16 + llo) * lg);

  f16x8 qaH[2][2], qaL[2][2];
#pragma unroll
  for (int rf = 0; rf < 2; ++rf)
#pragma unroll
    for (int kt = 0; kt < 2; ++kt) {
      size_t qo = (size_t)(wrow0 + rf * 16 + llo) * DKH + kt * 32 + lhi * 8;
      qaH[rf][kt] = *(const f16x8*)(qbhH + qo);
      qaL[rf][kt] = *(const f16x8*)(qbhL + qo);
    }

  const f32x4 fz = {0.f, 0.f, 0.f, 0.f};
  f32x4 acc[2][8];
#pragma unroll
  for (int i = 0; i < 2; ++i)
#pragma unroll
    for (int j = 0; j < 8; ++j) acc[i][j] = fz;
  float dsum[2][4] = {{0, 0, 0, 0}, {0, 0, 0, 0}};

  {
    const bool diag = (ctc == rb);
    float fn[2][4];
#pragma unroll
    for (int rf = 0; rf < 2; ++rf)
#pragma unroll
      for (int rg = 0; rg < 4; ++rg) {
        int n = wrow0 + rf * 16 + lhi * 4 + rg;
        fn[rf][rg] = expf((float)(n - ctc * 128) * lg) * invn[rf][rg];
      }

#pragma unroll
    for (int fc = 0; fc < 8; ++fc) {
      f32x4 pH[2] = {fz, fz}, pM[2] = {fz, fz};
#pragma unroll
      for (int kt = 0; kt < 2; ++kt) {
        size_t kro = (size_t)(ctc * 128 + fc * 16 + llo) * DKH + kt * 32 + lhi * 8;
        f16x8 kbH = *(const f16x8*)(kbhH + kro);
        f16x8 kbL = *(const f16x8*)(kbhL + kro);
        pH[0] = __builtin_amdgcn_mfma_f32_16x16x32_f16(qaH[0][kt], kbH, pH[0], 0, 0, 0);
        pH[1] = __builtin_amdgcn_mfma_f32_16x16x32_f16(qaH[1][kt], kbH, pH[1], 0, 0, 0);
        pM[0] = __builtin_amdgcn_mfma_f32_16x16x32_f16(qaL[0][kt], kbH, pM[0], 0, 0, 0);
        pM[1] = __builtin_amdgcn_mfma_f32_16x16x32_f16(qaL[1][kt], kbH, pM[1], 0, 0, 0);
        pM[0] = __builtin_amdgcn_mfma_f32_16x16x32_f16(qaH[0][kt], kbL, pM[0], 0, 0, 0);
        pM[1] = __builtin_amdgcn_mfma_f32_16x16x32_f16(qaH[1][kt], kbL, pM[1], 0, 0, 0);
      }
#pragma unroll
      for (int rf = 0; rf < 2; ++rf)
#pragma unroll
        for (int rg = 0; rg < 4; ++rg) {
          float pv = (pH[rf][rg] + pM[rf][rg] * (1.f / 1024.f)) * fn[rf][rg] * gm[fc];
          if (diag) {
            int e = (wrow0 + rf * 16 + lhi * 4 + rg) - (ctc * 128 + fc * 16 + llo);
            if (e < 0) pv = 0.f;
          }
          dsum[rf][rg] += fabsf(pv);
          int prow = rf * 16 + lhi * 4 + rg;
          int byte = (w << 13) + prow * 256 + (fc * 16 + llo) * 2;
          byte ^= (prow & 7) << 4;
          *(_Float16*)(pbuf + byte) = (_Float16)pv;
        }
    }
    // each wave reads only its own pbuf slice — no barrier needed

    f16x8 pa[2][4];
#pragma unroll
    for (int rf2 = 0; rf2 < 2; ++rf2)
#pragma unroll
      for (int kt = 0; kt < 4; ++kt) {
        int prow = rf2 * 16 + llo;
        int byte = (w << 13) + prow * 256 + kt * 64 + lhi * 16;
        byte ^= (prow & 7) << 4;
        pa[rf2][kt] = *(const f16x8*)(pbuf + byte);
      }
#pragma unroll
    for (int fd = 0; fd < 8; ++fd)
#pragma unroll
      for (int kt = 0; kt < 4; ++kt) {
        f16x8 vb = *(const f16x8*)(vbh + (size_t)(fd * 16 + llo) * SEQ + ctc * 128 + kt * 32 + lhi * 8);
        acc[0][fd] = __builtin_amdgcn_mfma_f32_16x16x32_f16(pa[0][kt], vb, acc[0][fd], 0, 0, 0);
        acc[1][fd] = __builtin_amdgcn_mfma_f32_16x16x32_f16(pa[1][kt], vb, acc[1][fd], 0, 0, 0);
      }
  }

  float* ab = accb + (size_t)bh * SEQ * DVH;
#pragma unroll
  for (int rf = 0; rf < 2; ++rf)
#pragma unroll
    for (int rg = 0; rg < 4; ++rg) {
      float d = dsum[rf][rg];
      d += __shfl_xor(d, 1); d += __shfl_xor(d, 2);
      d += __shfl_xor(d, 4); d += __shfl_xor(d, 8);
      int row = wrow0 + rf * 16 + lhi * 4 + rg;
      if (llo == 0) atomicAdd(&dsacc[bh * SEQ + row], d);
#pragma unroll
      for (int fd = 0; fd < 8; ++fd)
        atomicAdd(&ab[(size_t)row * DVH + fd * 16 + llo], acc[rf][fd][rg]);
    }
}

// =====================================================================
// retention stage 2: row-normalize + group-norm + silu(g)*o fused,
// g read as f16 dense [row][1536]; writes ogb f16 [B*S][1536].
// ALSO re-zeroes accb/dsacc after consuming (each element owned by
// exactly one thread) so the next layer's atomics start from 0.
// =====================================================================
__global__ __launch_bounds__(256) void attn_norm(float* __restrict__ accb,
                                                 float* __restrict__ dsacc,
                                                 const _Float16* __restrict__ gsrc,
                                                 _Float16* __restrict__ oh)
{
  int bh = blockIdx.y, h = bh % NH, b = bh / NH;
  int s0 = blockIdx.x * 32;
  int lane = threadIdx.x & 63, w = threadIdx.x >> 6;
  float* ab = accb + ((size_t)bh * SEQ + s0) * DVH;
#pragma unroll
  for (int i = 0; i < 8; ++i) {
    int r = w * 8 + i;
    size_t row = (size_t)(b * SEQ + s0 + r);
    float2 v = *(const float2*)(ab + (size_t)r * DVH + lane * 2);
    float inv = 1.f / fmaxf(dsacc[bh * SEQ + s0 + r], 1.f);
    // consume-and-clear: next layer's atomics need zeroed buffers
    float2 zz = {0.f, 0.f};
    *(float2*)(ab + (size_t)r * DVH + lane * 2) = zz;
    v.x *= inv; v.y *= inv;
    float ss = v.x * v.x + v.y * v.y;
#pragma unroll
    for (int m = 1; m < 64; m <<= 1) ss += __shfl_xor(ss, m);
    float rs = rsqrtf(ss * (1.f / 128.f) + 1e-5f);
    float o0 = v.x * rs, o1 = v.y * rs;
    f16x2 gg = *(const f16x2*)(gsrc + row * DVAL + h * DVH + lane * 2);
    float gx = (float)gg[0], gy = (float)gg[1];
    float y0 = gx / (1.f + expf(-gx)) * o0;
    float y1 = gy / (1.f + expf(-gy)) * o1;
    f16x2 vh = {(_Float16)y0, (_Float16)y1};
    *(f16x2*)(oh + row * DVAL + h * DVH + lane * 2) = vh;
    if (lane == 0) dsacc[bh * SEQ + s0 + r] = 0.f;
  }
}

// =====================================================================
// mean pool over S
// =====================================================================
__global__ void pool_kernel(const float* __restrict__ xf, float* __restrict__ pooled)
{
  int d = blockIdx.x * 256 + threadIdx.x;   // grid.x = 3
  int b = blockIdx.y;
  float acc = 0.f;
  for (int s = 0; s < SEQ; ++s) acc += xf[((size_t)(b * SEQ + s)) * DMOD + d];
  pooled[b * DMOD + d] = acc * (1.f / SEQ);
}

// =====================================================================
// classifier
// =====================================================================
__global__ void clf_kernel(const float* __restrict__ pooled, const float* __restrict__ cw,
                           const float* __restrict__ cb, float* __restrict__ out)
{
  int b = blockIdx.x, c = threadIdx.x;
  if (c < 100) {
    float acc = cb[c];
    for (int d = 0; d < DMOD; ++d) acc += pooled[b * DMOD + d] * cw[d * 100 + c];
    out[b * 100 + c] = acc;
  }
}

// =====================================================================
// host
// =====================================================================
extern "C" void kernel_launch(void* const* d_in, const int* in_sizes, int n_in,
                              void* d_out, int out_size, void* d_ws, size_t ws_size,
                              hipStream_t stream)
{
  const int*   ids  = (const int*)d_in[0];
  const float* emb  = (const float*)d_in[1];
  const float* wq   = (const float*)d_in[2];
  const float* wk   = (const float*)d_in[3];
  const float* wv   = (const float*)d_in[4];
  const float* wg   = (const float*)d_in[5];
  const float* wo   = (const float*)d_in[6];
  const float* ln1g = (const float*)d_in[7];
  const float* ln1b = (const float*)d_in[8];
  const float* ln2g = (const float*)d_in[9];
  const float* ln2b = (const float*)d_in[10];
  const float* fc1  = (const float*)d_in[11];
  const float* gate = (const float*)d_in[12];
  const float* fc2  = (const float*)d_in[13];
  const float* lnfg = (const float*)d_in[14];
  const float* lnfb = (const float*)d_in[15];
  const float* clfw = (const float*)d_in[16];
  const float* clfb = (const float*)d_in[17];
  float* out = (float*)d_out;

  char* ws = (char*)d_ws;
  size_t off = 0;
  auto alloc = [&](size_t bytes) {
    size_t r = off;
    off = (off + bytes + 255) & ~(size_t)255;
    return r;
  };

  const size_t W_QKVG = 12ull * 4608 * 768 * 2;
  const size_t W_O    = 12ull * 768 * 1536 * 2;
  const size_t W_F1GT = 12ull * 6144 * 768 * 2;
  const size_t W_F2   = 12ull * 768 * 3072 * 2;
  const bool big = ws_size >= 720ull * 1024 * 1024;
  const size_t d12 = big ? 1 : 12;

  _Float16* wQKVGh = (_Float16*)(ws + alloc(W_QKVG / d12));
  _Float16* wQKVGl = (_Float16*)(ws + alloc(W_QKVG / d12));
  _Float16* wOh    = (_Float16*)(ws + alloc(W_O    / d12));
  _Float16* wOl    = (_Float16*)(ws + alloc(W_O    / d12));
  _Float16* wF1GTh = (_Float16*)(ws + alloc(W_F1GT / d12));
  _Float16* wF1GTl = (_Float16*)(ws + alloc(W_F1GT / d12));
  _Float16* wF2h   = (_Float16*)(ws + alloc(W_F2   / d12));
  _Float16* wF2l   = (_Float16*)(ws + alloc(W_F2   / d12));

  float*    x    = (float*)(ws + alloc((size_t)BS * DMOD * 4));
  _Float16* hbfH = (_Float16*)(ws + alloc((size_t)BS * DMOD * 2));
  float*    cbuf = (float*)(ws + alloc((size_t)BS * DMOD * 4));   // final-LN scratch
  char*     regB = ws + alloc(8ull * 6291456);                    // 50.3 MB
  float*    accb = (float*)(ws + alloc((size_t)BS * DVAL * 4 + 48ull * SEQ * 4));
  float*    dsacc = accb + (size_t)BS * DVAL;
  float*    ctab = (float*)(ws + alloc(1024 * 32 * 4));
  float*    stab = (float*)(ws + alloc(1024 * 32 * 4));
  float*    pooled = (float*)(ws + alloc(4 * DMOD * 4));

  _Float16* qrbH = (_Float16*)regB;
  _Float16* qrbL = (_Float16*)(regB + 6291456);
  _Float16* krbH = (_Float16*)(regB + 12582912);
  _Float16* krbL = (_Float16*)(regB + 18874368);
  _Float16* vtb  = (_Float16*)(regB + 25165824);
  _Float16* gbuf = (_Float16*)(regB + 37748736);    // 12.58 MB, after vtb
  _Float16* ogbH = (_Float16*)regB;                 // alias (post-attn_part)
  _Float16* ffnbH = (_Float16*)regB;                // alias (post-wo)

  dim3 tb(32, 8);
  const long lsDD = 768l * 768, lsDV = 768l * 1536, lsDF = 768l * 3072;
  const long oQKVG = 4608l * 768, oO = 768l * 1536, oF1 = 6144l * 768, oF2 = 768l * 3072;

  trig_kernel<<<1024, 32, 0, stream>>>(ctab, stab);
  // one upfront clear (handles 0xAA poison); attn_norm re-zeroes per layer
  hipMemsetAsync(accb, 0, (size_t)BS * DVAL * 4 + 48ull * SEQ * 4, stream);

  if (big) {
    wcvt_kernel<<<dim3(24, 24, 12), tb, 0, stream>>>(wq,   wQKVGh, wQKVGl, 768, 768,  lsDD, oQKVG, 0,    0);
    wcvt_kernel<<<dim3(24, 24, 12), tb, 0, stream>>>(wk,   wQKVGh, wQKVGl, 768, 768,  lsDD, oQKVG, 768,  0);
    wcvt_kernel<<<dim3(48, 24, 12), tb, 0, stream>>>(wv,   wQKVGh, wQKVGl, 768, 1536, lsDV, oQKVG, 1536, 0);
    wcvt_kernel<<<dim3(48, 24, 12), tb, 0, stream>>>(wg,   wQKVGh, wQKVGl, 768, 1536, lsDV, oQKVG, 3072, 0);
    wcvt_kernel<<<dim3(24, 48, 12), tb, 0, stream>>>(wo,   wOh,    wOl,    1536, 768, lsDV, oO,    0,    0);
    wcvt_kernel<<<dim3(96, 24, 12), tb, 0, stream>>>(fc1,  wF1GTh, wF1GTl, 768, 3072, lsDF, oF1,   0,    1);
    wcvt_kernel<<<dim3(96, 24, 12), tb, 0, stream>>>(gate, wF1GTh, wF1GTl, 768, 3072, lsDF, oF1,   0,    2);
    wcvt_kernel<<<dim3(24, 96, 12), tb, 0, stream>>>(fc2,  wF2h,   wF2l,   3072, 768, lsDF, oF2,   0,    0);
  }

  embed_kernel<<<BS, 192, 0, stream>>>(ids, emb, x);

  for (int l = 0; l < 12; ++l) {
    const _Float16 *Wqkh, *Wqkl, *Woh_, *Wol_, *Wfh, *Wfl, *W2h, *W2l;
    if (big) {
      Wqkh = wQKVGh + (size_t)l * oQKVG;  Wqkl = wQKVGl + (size_t)l * oQKVG;
      Woh_ = wOh    + (size_t)l * oO;     Wol_ = wOl    + (size_t)l * oO;
      Wfh  = wF1GTh + (size_t)l * oF1;    Wfl  = wF1GTl + (size_t)l * oF1;
      W2h  = wF2h   + (size_t)l * oF2;    W2l  = wF2l   + (size_t)l * oF2;
    } else {
      wcvt_kernel<<<dim3(24, 24, 1), tb, 0, stream>>>(wq   + (size_t)l * lsDD, wQKVGh, wQKVGl, 768, 768,  0, 0, 0,    0);
      wcvt_kernel<<<dim3(24, 24, 1), tb, 0, stream>>>(wk   + (size_t)l * lsDD, wQKVGh, wQKVGl, 768, 768,  0, 0, 768,  0);
      wcvt_kernel<<<dim3(48, 24, 1), tb, 0, stream>>>(wv   + (size_t)l * lsDV, wQKVGh, wQKVGl, 768, 1536, 0, 0, 1536, 0);
      wcvt_kernel<<<dim3(48, 24, 1), tb, 0, stream>>>(wg   + (size_t)l * lsDV, wQKVGh, wQKVGl, 768, 1536, 0, 0, 3072, 0);
      wcvt_kernel<<<dim3(24, 48, 1), tb, 0, stream>>>(wo   + (size_t)l * lsDV, wOh,    wOl,    1536, 768, 0, 0, 0,    0);
      wcvt_kernel<<<dim3(96, 24, 1), tb, 0, stream>>>(fc1  + (size_t)l * lsDF, wF1GTh, wF1GTl, 768, 3072, 0, 0, 0,    1);
      wcvt_kernel<<<dim3(96, 24, 1), tb, 0, stream>>>(gate + (size_t)l * lsDF, wF1GTh, wF1GTl, 768, 3072, 0, 0, 0,    2);
      wcvt_kernel<<<dim3(24, 96, 1), tb, 0, stream>>>(fc2  + (size_t)l * lsDF, wF2h,   wF2l,   3072, 768, 0, 0, 0,    0);
      Wqkh = wQKVGh; Wqkl = wQKVGl; Woh_ = wOh; Wol_ = wOl;
      Wfh = wF1GTh; Wfl = wF1GTl; W2h = wF2h; W2l = wF2l;
    }

    ln_h_kernel<<<BS, 256, 0, stream>>>(x, ln1g + l * 768, ln1b + l * 768, hbfH);
    // fused qkvg: 256x128 tile, 8 waves
    gemm_bt<256, 3, 512><<<36 * 16, 512, 0, stream>>>(hbfH, Wqkh, Wqkl, nullptr, nullptr,
                                                      nullptr, qrbH, qrbL, krbH, krbL,
                                                      vtb, gbuf, ctab, stab,
                                                      36, 16, 768, 768, 0);
    attn_part<<<1728, 256, 0, stream>>>(qrbH, qrbL, krbH, krbL, vtb, accb, dsacc);
    attn_norm<<<dim3(32, 48), 256, 0, stream>>>(accb, dsacc, gbuf, ogbH);
    // wo: split-K x2, partials atomically accumulate into x (holds residual)
    gemm_bt<64, 2, 256><<<6 * 64 * 2, 256, 0, stream>>>(ogbH, Woh_, Wol_, x, nullptr,
                                                        nullptr, nullptr, nullptr, nullptr,
                                                        nullptr, nullptr, nullptr, nullptr,
                                                        nullptr, 6, 64, 1536, 768, 768);
    ln_h_kernel<<<BS, 256, 0, stream>>>(x, ln2g + l * 768, ln2b + l * 768, hbfH);
    // f1gt: 256x128 tile, 8 waves, fused silu-gate epilogue
    gemm_bt<256, 1, 512><<<48 * 16, 512, 0, stream>>>(hbfH, Wfh, Wfl, nullptr, nullptr,
                                                      ffnbH, nullptr, nullptr, nullptr,
                                                      nullptr, nullptr, nullptr, nullptr,
                                                      nullptr, 48, 16, 768, 768, 0);
    // f2: split-K x4
    gemm_bt<64, 2, 256><<<6 * 64 * 4, 256, 0, stream>>>(ffnbH, W2h, W2l, x, nullptr,
                                                        nullptr, nullptr, nullptr, nullptr,
                                                        nullptr, nullptr, nullptr, nullptr,
                                                        nullptr, 6, 64, 3072, 768, 768);
  }

  float* xf = cbuf;
  ln_kernel<<<BS, 256, 0, stream>>>(x, lnfg, lnfb, xf);
  pool_kernel<<<dim3(3, 4), 256, 0, stream>>>(xf, pooled);
  clf_kernel<<<4, 128, 0, stream>>>(pooled, clfw, clfb, out);
}